// Round 18
// baseline (451.648 us; speedup 1.0000x reference)
//
#include <hip/hip_runtime.h>
#include <hip/hip_bf16.h>

// ---------------------------------------------------------------------------
// GCN via device-built CSR, all tensors bf16, all GEMMs MFMA.
//   k_wt: W1..W3 -> WT bf16 [n][k]; Wlin -> WTL bf16 [n][384]
//   mega0 = [gemm1 MFMA (f32 x -> bf16 in staging) | deg, XCD-partitioned]
//   scan1 ; scan3f ; k_fill (XCD-partitioned scatter)
//   3x [ agg -> hcat bf16 ; gemm_{k+1} MFMA ] ; final MFMA
// XCD partition (r17, -55us): block handles col-range blockIdx%8 reading the
// whole edge stream -> cursor/deg/sorted_row lines written by ONE XCD.
// r18: (a) nontemporal edge-stream loads (don't evict L2 write-combining
// lines -- r17 fill WRITE was 75MB vs 6.4MB payload = read-thrash evictions);
// (b) batch 8K-edge chunk into regs upfront -> 32 independent atomic chains
// per lane (r17 VGPR=8 showed the compiler serialized the atomic->store deps).
// MFMA: mfma_f32_32x32x16_bf16, LDS XOR swizzle byte^=(row&7)<<4,
// C/D map col=lane&31, row=(q&3)+8*(q>>2)+4*(lane>>5) [verified r13/r14].
// ---------------------------------------------------------------------------

typedef __attribute__((ext_vector_type(8))) short bf16x8;
typedef __attribute__((ext_vector_type(16))) float f32x16;
typedef int intv4 __attribute__((ext_vector_type(4)));

__device__ __forceinline__ unsigned short f2bf(float f) {  // RNE f32->bf16
  unsigned int u = __float_as_uint(f);
  u += 0x7FFFu + ((u >> 16) & 1u);
  return (unsigned short)(u >> 16);
}
__device__ __forceinline__ unsigned int bfpack(float a, float b) {
  return ((unsigned int)f2bf(a)) | ((unsigned int)f2bf(b) << 16);
}
__device__ __forceinline__ void bf4_unpack(uint2 v, float* f) {
  f[0] = __uint_as_float(v.x << 16); f[1] = __uint_as_float(v.x & 0xFFFF0000u);
  f[2] = __uint_as_float(v.y << 16); f[3] = __uint_as_float(v.y & 0xFFFF0000u);
}

// ---- weight transposes: W1..W3 -> WT[128][128]; Wlin -> WTL[64][384] ------
__global__ __launch_bounds__(256) void k_wt(
    const float* __restrict__ W1, const float* __restrict__ W2,
    const float* __restrict__ W3, const float* __restrict__ Wlin,
    unsigned short* __restrict__ WT1, unsigned short* __restrict__ WT2,
    unsigned short* __restrict__ WT3, unsigned short* __restrict__ WTL) {
  const int idx = blockIdx.x * 256 + threadIdx.x;  // 49152 + 24576
  if (idx < 49152) {
    const int w = idx >> 14;
    const int rem = idx & 16383;
    const int n = rem >> 7, k = rem & 127;
    const float* W = (w == 0) ? W1 : (w == 1) ? W2 : W3;
    unsigned short* WT = (w == 0) ? WT1 : (w == 1) ? WT2 : WT3;
    WT[n * 128 + k] = f2bf(W[k * 128 + n]);
  } else if (idx < 49152 + 24576) {
    const int rem = idx - 49152;
    const int n = rem / 384, k = rem - n * 384;
    WTL[n * 384 + k] = f2bf(Wlin[k * 64 + n]);
  }
}

// ---- MFMA GEMM body, f32 A input (convert in staging), BK=64 --------------
__device__ __forceinline__ void gemm_mfma_f32in_body(
    const float* __restrict__ A, const unsigned short* __restrict__ WT,
    unsigned short* __restrict__ hw, int N, int n0, char* hsb, char* wsb) {
  const int tid = threadIdx.x;
  const int rows = min(128, N - n0);
  const int l = tid & 63;
  const int m0 = (tid >> 6) << 5;
  const int lm = l & 31;
  const int lkb = (l >> 5) << 4;       // K byte sub-offset: 0 or 16
  const int ra = m0 + lm;
  f32x16 acc[4];
  #pragma unroll
  for (int t = 0; t < 4; ++t)
    #pragma unroll
    for (int q = 0; q < 16; ++q) acc[t][q] = 0.f;

  for (int kc = 0; kc < 128; kc += 64) {
    #pragma unroll
    for (int u = 0; u < 4; ++u) {     // stage A chunk: 128 rows x 64 K, f32->bf16
      const int i = tid + 256 * u;
      const int r = i >> 3, k8 = (i & 7) << 3;
      uint4 o = make_uint4(0u, 0u, 0u, 0u);
      if (r < rows) {
        const float* ap = A + (size_t)(n0 + r) * 128 + kc + k8;
        const float4 a = *(const float4*)(ap);
        const float4 b = *(const float4*)(ap + 4);
        o.x = bfpack(a.x, a.y); o.y = bfpack(a.z, a.w);
        o.z = bfpack(b.x, b.y); o.w = bfpack(b.z, b.w);
      }
      *(uint4*)(hsb + ((r * 128 + k8 * 2) ^ ((r & 7) << 4))) = o;
    }
    #pragma unroll
    for (int u = 0; u < 4; ++u) {     // stage WT chunk: 128 n x 64 K (bf16)
      const int i = tid + 256 * u;
      const int nn = i >> 3, k8 = (i & 7) << 3;
      const uint4 v = *(const uint4*)(WT + nn * 128 + kc + k8);
      *(uint4*)(wsb + ((nn * 128 + k8 * 2) ^ ((nn & 7) << 4))) = v;
    }
    __syncthreads();
    #pragma unroll
    for (int ks = 0; ks < 4; ++ks) {
      const int kb = ks * 32 + lkb;
      const bf16x8 af = *(const bf16x8*)(hsb + ((ra * 128 + kb) ^ ((ra & 7) << 4)));
      #pragma unroll
      for (int t = 0; t < 4; ++t) {
        const int rb = t * 32 + lm;
        const bf16x8 bfr = *(const bf16x8*)(wsb + ((rb * 128 + kb) ^ ((rb & 7) << 4)));
        acc[t] = __builtin_amdgcn_mfma_f32_32x32x16_bf16(af, bfr, acc[t], 0, 0, 0);
      }
    }
    __syncthreads();
  }

  #pragma unroll
  for (int t = 0; t < 4; ++t) {
    #pragma unroll
    for (int q = 0; q < 16; ++q) {
      const int m = m0 + (q & 3) + ((q >> 2) << 3) + ((l >> 5) << 2);
      if (m < rows) hw[(size_t)(n0 + m) * 128 + t * 32 + lm] = f2bf(acc[t][q]);
    }
  }
}

// ---- mega0: [gemm1 MFMA (blocks first) | deg count, XCD-partitioned] ------
__global__ __launch_bounds__(256, 2) void k_mega0(
    const float* __restrict__ x, const unsigned short* __restrict__ WT1,
    unsigned short* __restrict__ hw, int N, int gb,
    const int* __restrict__ coli, int E, int* __restrict__ degi) {
  __shared__ __align__(16) unsigned short hs[128 * 64];   // 16KB
  __shared__ __align__(16) unsigned short wsm[128 * 64];  // 16KB
  if ((int)blockIdx.x < gb) {
    gemm_mfma_f32in_body(x, WT1, hw, N, blockIdx.x * 128, (char*)hs, (char*)wsm);
  } else {
    const int bb = (int)blockIdx.x - gb;
    const int xcd = (int)blockIdx.x & 7;   // presumed XCD (round-robin)
    const int chunk = bb >> 3;
    const int nsz = (N + 7) >> 3;
    const int clo = xcd * nsz;
    const int chi = min(clo + nsz, N);
    const int ebase = chunk * 8192 + (int)threadIdx.x * 4;
    intv4 c[8];
    #pragma unroll
    for (int it = 0; it < 8; ++it) {   // batch: 8 nt-loads upfront
      const int e = ebase + it * 1024;
      if (e + 3 < E) {
        c[it] = __builtin_nontemporal_load((const intv4*)(coli + e));
      } else {
        intv4 cc = {-1, -1, -1, -1};
        for (int q = 0; q < 4; ++q) if (e + q < E) cc[q] = coli[e + q];
        c[it] = cc;
      }
    }
    #pragma unroll
    for (int it = 0; it < 8; ++it)
      #pragma unroll
      for (int q = 0; q < 4; ++q) {
        const int cc = c[it][q];
        if (cc >= clo && cc < chi) atomicAdd(&degi[cc], 1);
      }
  }
}

// ---- scan1: dense deg -> dinv + block-local offs + bsums ------------------
__global__ __launch_bounds__(256) void k_scan1(
    const int* __restrict__ degi, int N, int* __restrict__ offs,
    int* __restrict__ bsums, float* __restrict__ dinv) {
  __shared__ int sm[256];
  const int b = blockIdx.x, t = threadIdx.x;
  const int base = b * 1024 + t * 4;
  int v[4];
  #pragma unroll
  for (int i = 0; i < 4; ++i) v[i] = (base + i < N) ? degi[base + i] : 0;
  #pragma unroll
  for (int i = 0; i < 4; ++i)
    if (base + i < N) dinv[base + i] = rsqrtf(1.0f + (float)v[i]);
  const int s = v[0] + v[1] + v[2] + v[3];
  sm[t] = s;
  __syncthreads();
  for (int ofs = 1; ofs < 256; ofs <<= 1) {
    const int add = (t >= ofs) ? sm[t - ofs] : 0;
    __syncthreads();
    sm[t] += add;
    __syncthreads();
  }
  if (t == 255) bsums[b] = sm[255];
  int run = sm[t] - s;
  #pragma unroll
  for (int i = 0; i < 4; ++i) {
    if (base + i < N) offs[base + i] = run;
    run += v[i];
  }
}

// ---- scan3f (fused scan2+3): global offsets + cursor init -----------------
__global__ __launch_bounds__(256) void k_scan3f(
    int* __restrict__ offs, const int* __restrict__ bsums,
    int* __restrict__ cursor, int nb, int N) {
  __shared__ int sm[128];
  const int t = threadIdx.x;
  if (t < 128) sm[t] = (t < nb) ? bsums[t] : 0;
  __syncthreads();
  for (int ofs = 1; ofs < 128; ofs <<= 1) {
    int add = 0;
    if (t < 128 && t >= ofs) add = sm[t - ofs];
    __syncthreads();
    if (t < 128) sm[t] += add;
    __syncthreads();
  }
  const int add = (blockIdx.x == 0) ? 0 : sm[blockIdx.x - 1];
  const int base = blockIdx.x * 1024 + t * 4;
  #pragma unroll
  for (int i = 0; i < 4; ++i) {
    const int idx = base + i;
    if (idx < N) {
      const int o = offs[idx] + add;
      offs[idx] = o;
      cursor[idx] = o;
    }
  }
}

// ---- fill: XCD-partitioned scatter, nt edge loads, deep atomic batch ------
__global__ __launch_bounds__(256) void k_fill(
    const int* __restrict__ rowi, const int* __restrict__ coli,
    int* __restrict__ cursor, int* __restrict__ sorted_row, int E, int N) {
  const int xcd = (int)blockIdx.x & 7;   // presumed XCD (round-robin)
  const int chunk = (int)blockIdx.x >> 3;
  const int nsz = (N + 7) >> 3;
  const int clo = xcd * nsz;
  const int chi = min(clo + nsz, N);
  const int ebase = chunk * 8192 + (int)threadIdx.x * 4;
  intv4 c[8], r[8];
  #pragma unroll
  for (int it = 0; it < 8; ++it) {   // batch: 16 nt-loads upfront
    const int e = ebase + it * 1024;
    if (e + 3 < E) {
      c[it] = __builtin_nontemporal_load((const intv4*)(coli + e));
      r[it] = __builtin_nontemporal_load((const intv4*)(rowi + e));
    } else {
      intv4 cc = {-1, -1, -1, -1}, rr = {0, 0, 0, 0};
      for (int q = 0; q < 4; ++q)
        if (e + q < E) { cc[q] = coli[e + q]; rr[q] = rowi[e + q]; }
      c[it] = cc; r[it] = rr;
    }
  }
  #pragma unroll
  for (int it = 0; it < 8; ++it)     // 32 independent atomic->store chains
    #pragma unroll
    for (int q = 0; q < 4; ++q) {
      const int cc = c[it][q];
      if (cc >= clo && cc < chi) {
        const int p = atomicAdd(&cursor[cc], 1);
        sorted_row[p] = r[it][q];
      }
    }
}

// ---- MFMA GEMM (layers 2,3): full-K 64KB LDS (proven r13) -----------------
__global__ __launch_bounds__(256, 2) void k_gemm_mfma(
    const unsigned short* __restrict__ A, long long lda,
    const unsigned short* __restrict__ WT, unsigned short* __restrict__ hw,
    int N) {
  __shared__ __align__(16) unsigned short hs[128 * 128];
  __shared__ __align__(16) unsigned short WsT[128 * 128];
  const int tid = threadIdx.x;
  const int n0 = blockIdx.x * 128;
  const int rows = min(128, N - n0);
  char* hsb = (char*)hs;
  char* wsb = (char*)WsT;

  #pragma unroll
  for (int u = 0; u < 8; ++u) {
    const int i = tid + 256 * u;
    const int r = i >> 4, k8 = (i & 15) << 3;
    uint4 v = make_uint4(0u, 0u, 0u, 0u);
    if (r < rows) v = *(const uint4*)(A + (size_t)(n0 + r) * lda + k8);
    *(uint4*)(hsb + ((r * 256 + k8 * 2) ^ ((r & 7) << 4))) = v;
  }
  #pragma unroll
  for (int u = 0; u < 8; ++u) {
    const int i = tid + 256 * u;
    const int nn = i >> 4, k8 = (i & 15) << 3;
    const uint4 v = *(const uint4*)(WT + nn * 128 + k8);
    *(uint4*)(wsb + ((nn * 256 + k8 * 2) ^ ((nn & 7) << 4))) = v;
  }
  __syncthreads();

  const int l = tid & 63;
  const int m0 = (tid >> 6) << 5;
  const int lm = l & 31;
  const int lk = (l >> 5) << 3;
  const int ra = m0 + lm;
  f32x16 acc[4];
  #pragma unroll
  for (int t = 0; t < 4; ++t)
    #pragma unroll
    for (int q = 0; q < 16; ++q) acc[t][q] = 0.f;

  #pragma unroll
  for (int ks = 0; ks < 8; ++ks) {
    const int kb = (ks * 16 + lk) * 2;
    const bf16x8 af = *(const bf16x8*)(hsb + ((ra * 256 + kb) ^ ((ra & 7) << 4)));
    #pragma unroll
    for (int t = 0; t < 4; ++t) {
      const int rb = t * 32 + lm;
      const bf16x8 bfr = *(const bf16x8*)(wsb + ((rb * 256 + kb) ^ ((rb & 7) << 4)));
      acc[t] = __builtin_amdgcn_mfma_f32_32x32x16_bf16(af, bfr, acc[t], 0, 0, 0);
    }
  }

  #pragma unroll
  for (int t = 0; t < 4; ++t) {
    #pragma unroll
    for (int q = 0; q < 16; ++q) {
      const int m = m0 + (q & 3) + ((q >> 2) << 3) + ((l >> 5) << 2);
      if (m < rows) hw[(size_t)(n0 + m) * 128 + t * 32 + lm] = f2bf(acc[t][q]);
    }
  }
}

// ---- MFMA final: out = hcat(bf16) @ Wlin + blin, 3 K-chunks of 128 --------
__global__ __launch_bounds__(256, 2) void k_final_mfma(
    const unsigned short* __restrict__ hcat, const unsigned short* __restrict__ WTL,
    const float* __restrict__ blin, float* __restrict__ out, int N) {
  __shared__ __align__(16) unsigned short hs[128 * 128];
  __shared__ __align__(16) unsigned short WsT[64 * 128];
  const int tid = threadIdx.x;
  const int n0 = blockIdx.x * 128;
  const int rows = min(128, N - n0);
  char* hsb = (char*)hs;
  char* wsb = (char*)WsT;

  const int l = tid & 63;
  const int m0 = (tid >> 6) << 5;
  const int lm = l & 31;
  const int lk = (l >> 5) << 3;
  const int ra = m0 + lm;
  f32x16 acc[2];
  #pragma unroll
  for (int t = 0; t < 2; ++t)
    #pragma unroll
    for (int q = 0; q < 16; ++q) acc[t][q] = 0.f;

  for (int kc = 0; kc < 384; kc += 128) {
    #pragma unroll
    for (int u = 0; u < 8; ++u) {
      const int i = tid + 256 * u;
      const int r = i >> 4, k8 = (i & 15) << 3;
      uint4 v = make_uint4(0u, 0u, 0u, 0u);
      if (r < rows) v = *(const uint4*)(hcat + (size_t)(n0 + r) * 384 + kc + k8);
      *(uint4*)(hsb + ((r * 256 + k8 * 2) ^ ((r & 7) << 4))) = v;
    }
    #pragma unroll
    for (int u = 0; u < 4; ++u) {
      const int i = tid + 256 * u;
      const int nn = i >> 4, k8 = (i & 15) << 3;
      const uint4 v = *(const uint4*)(WTL + nn * 384 + kc + k8);
      *(uint4*)(wsb + ((nn * 256 + k8 * 2) ^ ((nn & 7) << 4))) = v;
    }
    __syncthreads();

    #pragma unroll
    for (int ks = 0; ks < 8; ++ks) {
      const int kb = (ks * 16 + lk) * 2;
      const bf16x8 af = *(const bf16x8*)(hsb + ((ra * 256 + kb) ^ ((ra & 7) << 4)));
      #pragma unroll
      for (int t = 0; t < 2; ++t) {
        const int rb = t * 32 + lm;
        const bf16x8 bfr = *(const bf16x8*)(wsb + ((rb * 256 + kb) ^ ((rb & 7) << 4)));
        acc[t] = __builtin_amdgcn_mfma_f32_32x32x16_bf16(af, bfr, acc[t], 0, 0, 0);
      }
    }
    __syncthreads();
  }

  #pragma unroll
  for (int t = 0; t < 2; ++t) {
    const float bb = blin[t * 32 + lm];
    #pragma unroll
    for (int q = 0; q < 16; ++q) {
      const int m = m0 + (q & 3) + ((q >> 2) << 3) + ((l >> 5) << 2);
      if (m < rows) out[(size_t)(n0 + m) * 64 + t * 32 + lm] = acc[t][q] + bb;
    }
  }
}

// ---- segment aggregate (32 lanes/node, ushort4/lane, 8-deep gather) -------
__global__ __launch_bounds__(256) void k_agg(
    const int* __restrict__ offs, const int* __restrict__ degi,
    const int* __restrict__ sorted_row, const float* __restrict__ dinv,
    const unsigned short* __restrict__ hw, const float* __restrict__ bias,
    unsigned short* __restrict__ hcat, int koff, int N) {
  const int g = (int)((blockIdx.x * 256 + threadIdx.x) >> 5);
  if (g >= N) return;
  const int j = (threadIdx.x & 31) << 2;
  const float dc = dinv[g];
  float acc[4];
  {
    const uint2 sv = *(const uint2*)(hw + (size_t)g * 128 + j);
    float f[4];
    bf4_unpack(sv, f);
    #pragma unroll
    for (int q = 0; q < 4; ++q) acc[q] = dc * f[q];
  }

  const int off = offs[g];
  const int end = off + degi[g];
  int e = off;
  for (; e + 7 < end; e += 8) {
    int r[8];
    #pragma unroll
    for (int t = 0; t < 8; ++t) r[t] = sorted_row[e + t];
    float dr[8];
    uint2 v[8];
    #pragma unroll
    for (int t = 0; t < 8; ++t) {
      dr[t] = dinv[r[t]];
      v[t] = *(const uint2*)(hw + (size_t)r[t] * 128 + j);
    }
    #pragma unroll
    for (int t = 0; t < 8; ++t) {
      float f[4];
      bf4_unpack(v[t], f);
      #pragma unroll
      for (int q = 0; q < 4; ++q) acc[q] = fmaf(dr[t], f[q], acc[q]);
    }
  }
  for (; e + 3 < end; e += 4) {
    int r[4];
    #pragma unroll
    for (int t = 0; t < 4; ++t) r[t] = sorted_row[e + t];
    float dr[4];
    uint2 v[4];
    #pragma unroll
    for (int t = 0; t < 4; ++t) {
      dr[t] = dinv[r[t]];
      v[t] = *(const uint2*)(hw + (size_t)r[t] * 128 + j);
    }
    #pragma unroll
    for (int t = 0; t < 4; ++t) {
      float f[4];
      bf4_unpack(v[t], f);
      #pragma unroll
      for (int q = 0; q < 4; ++q) acc[q] = fmaf(dr[t], f[q], acc[q]);
    }
  }
  for (; e < end; ++e) {
    const int r0 = sorted_row[e];
    const float d0 = dinv[r0];
    const uint2 v0 = *(const uint2*)(hw + (size_t)r0 * 128 + j);
    float f[4];
    bf4_unpack(v0, f);
    #pragma unroll
    for (int q = 0; q < 4; ++q) acc[q] = fmaf(d0, f[q], acc[q]);
  }

  const float4 bb = *(const float4*)(bias + j);
  const float o0 = fmaxf(fmaf(dc, acc[0], bb.x), 0.f);
  const float o1 = fmaxf(fmaf(dc, acc[1], bb.y), 0.f);
  const float o2 = fmaxf(fmaf(dc, acc[2], bb.z), 0.f);
  const float o3 = fmaxf(fmaf(dc, acc[3], bb.w), 0.f);
  uint2 st;
  st.x = bfpack(o0, o1);
  st.y = bfpack(o2, o3);
  *(uint2*)(hcat + (size_t)g * 384 + koff + j) = st;
}

extern "C" void kernel_launch(void* const* d_in, const int* in_sizes, int n_in,
                              void* d_out, int out_size, void* d_ws, size_t ws_size,
                              hipStream_t stream) {
  const float* x    = (const float*)d_in[0];
  const int*   ei   = (const int*)d_in[1];
  const float* W1   = (const float*)d_in[2];
  const float* b1   = (const float*)d_in[3];
  const float* W2   = (const float*)d_in[4];
  const float* b2   = (const float*)d_in[5];
  const float* W3   = (const float*)d_in[6];
  const float* b3   = (const float*)d_in[7];
  const float* Wlin = (const float*)d_in[8];
  const float* blin = (const float*)d_in[9];

  const int N = in_sizes[0] / 128;
  const int E = in_sizes[1] / 2;
  const int* rowi = ei;
  const int* coli = ei + E;

  // ws: degi | cursor | dinv | offs | bsums | sorted_row | WT* | hw | hcat
  char* ws = (char*)d_ws;
  const size_t nb4 = (((size_t)N * 4) + 255) & ~(size_t)255;
  int*   degi       = (int*)ws;                 ws += nb4;
  int*   cursor     = (int*)ws;                 ws += nb4;
  float* dinv       = (float*)ws;               ws += nb4;
  int*   offs       = (int*)ws;                 ws += nb4;
  int*   bsums      = (int*)ws;                 ws += 1024;
  int*   sorted_row = (int*)ws;                 ws += (((size_t)E * 4) + 255) & ~(size_t)255;
  unsigned short* WT1  = (unsigned short*)ws;   ws += 128 * 128 * 2;
  unsigned short* WT2  = (unsigned short*)ws;   ws += 128 * 128 * 2;
  unsigned short* WT3  = (unsigned short*)ws;   ws += 128 * 128 * 2;
  unsigned short* WTL  = (unsigned short*)ws;   ws += 64 * 384 * 2;
  unsigned short* hw   = (unsigned short*)ws;   ws += (size_t)N * 128 * 2;
  unsigned short* hcat = (unsigned short*)ws;

  const int nblk = (N + 1023) / 1024;  // <= 128
  const int gemmBlocks = (N + 127) / 128;
  const int nCh = (E + 8191) / 8192;   // edge chunks of 8192
  const int partBlocks = nCh * 8;      // x8 XCD ranges
  const int aggBlocks  = (N + 7) / 8;

  k_wt<<<(49152 + 24576 + 255) / 256, 256, 0, stream>>>(W1, W2, W3, Wlin,
                                                        WT1, WT2, WT3, WTL);
  hipMemsetAsync(degi, 0, (size_t)N * 4, stream);
  k_mega0<<<gemmBlocks + partBlocks, 256, 0, stream>>>(x, WT1, hw, N, gemmBlocks,
                                                       coli, E, degi);
  k_scan1<<<nblk, 256, 0, stream>>>(degi, N, offs, bsums, dinv);
  k_scan3f<<<nblk, 256, 0, stream>>>(offs, bsums, cursor, nblk, N);
  k_fill<<<partBlocks, 256, 0, stream>>>(rowi, coli, cursor, sorted_row, E, N);

  k_agg<<<aggBlocks, 256, 0, stream>>>(offs, degi, sorted_row, dinv, hw,
                                       b1, hcat, 0, N);
  k_gemm_mfma<<<gemmBlocks, 256, 0, stream>>>(hcat, 384, WT2, hw, N);
  k_agg<<<aggBlocks, 256, 0, stream>>>(offs, degi, sorted_row, dinv, hw,
                                       b2, hcat, 128, N);
  k_gemm_mfma<<<gemmBlocks, 256, 0, stream>>>(hcat + 128, 384, WT3, hw, N);
  k_agg<<<aggBlocks, 256, 0, stream>>>(offs, degi, sorted_row, dinv, hw,
                                       b3, hcat, 256, N);
  k_final_mfma<<<gemmBlocks, 256, 0, stream>>>(hcat, WTL, blin, (float*)d_out, N);
}

// Round 19
// 419.338 us; speedup vs baseline: 1.0770x; 1.0770x over previous
//
#include <hip/hip_runtime.h>
#include <hip/hip_bf16.h>

// ---------------------------------------------------------------------------
// GCN via device-built CSR, all tensors bf16, all GEMMs MFMA.  (r17 config —
// best measured: 419us. r18's nt-loads + atomic batching both regressed and
// are reverted: the atomic floor is in the L2 atomic unit, not wave issue.)
//   k_wt: W1..W3 -> WT bf16 [n][k]; Wlin -> WTL bf16 [n][384]
//   mega0 = [gemm1 MFMA (f32 x -> bf16 in staging) | deg, XCD-partitioned]
//   scan1 ; scan3f ; k_fill (XCD-partitioned scatter)
//   3x [ agg -> hcat bf16 ; gemm_{k+1} MFMA ] ; final MFMA
// XCD partition (r17, -55us): block handles col-range blockIdx%8 reading the
// whole edge stream -> cursor/deg/sorted_row lines written by ONE XCD ->
// L2 write-combining instead of 64B-line ping-pong.
// MFMA: mfma_f32_32x32x16_bf16, LDS XOR swizzle byte^=(row&7)<<4,
// C/D map col=lane&31, row=(q&3)+8*(q>>2)+4*(lane>>5) [verified r13/r14].
// ---------------------------------------------------------------------------

typedef __attribute__((ext_vector_type(8))) short bf16x8;
typedef __attribute__((ext_vector_type(16))) float f32x16;

__device__ __forceinline__ unsigned short f2bf(float f) {  // RNE f32->bf16
  unsigned int u = __float_as_uint(f);
  u += 0x7FFFu + ((u >> 16) & 1u);
  return (unsigned short)(u >> 16);
}
__device__ __forceinline__ unsigned int bfpack(float a, float b) {
  return ((unsigned int)f2bf(a)) | ((unsigned int)f2bf(b) << 16);
}
__device__ __forceinline__ void bf4_unpack(uint2 v, float* f) {
  f[0] = __uint_as_float(v.x << 16); f[1] = __uint_as_float(v.x & 0xFFFF0000u);
  f[2] = __uint_as_float(v.y << 16); f[3] = __uint_as_float(v.y & 0xFFFF0000u);
}

// ---- weight transposes: W1..W3 -> WT[128][128]; Wlin -> WTL[64][384] ------
__global__ __launch_bounds__(256) void k_wt(
    const float* __restrict__ W1, const float* __restrict__ W2,
    const float* __restrict__ W3, const float* __restrict__ Wlin,
    unsigned short* __restrict__ WT1, unsigned short* __restrict__ WT2,
    unsigned short* __restrict__ WT3, unsigned short* __restrict__ WTL) {
  const int idx = blockIdx.x * 256 + threadIdx.x;  // 49152 + 24576
  if (idx < 49152) {
    const int w = idx >> 14;
    const int rem = idx & 16383;
    const int n = rem >> 7, k = rem & 127;
    const float* W = (w == 0) ? W1 : (w == 1) ? W2 : W3;
    unsigned short* WT = (w == 0) ? WT1 : (w == 1) ? WT2 : WT3;
    WT[n * 128 + k] = f2bf(W[k * 128 + n]);
  } else if (idx < 49152 + 24576) {
    const int rem = idx - 49152;
    const int n = rem / 384, k = rem - n * 384;
    WTL[n * 384 + k] = f2bf(Wlin[k * 64 + n]);
  }
}

// ---- MFMA GEMM body, f32 A input (convert in staging), BK=64 --------------
__device__ __forceinline__ void gemm_mfma_f32in_body(
    const float* __restrict__ A, const unsigned short* __restrict__ WT,
    unsigned short* __restrict__ hw, int N, int n0, char* hsb, char* wsb) {
  const int tid = threadIdx.x;
  const int rows = min(128, N - n0);
  const int l = tid & 63;
  const int m0 = (tid >> 6) << 5;
  const int lm = l & 31;
  const int lkb = (l >> 5) << 4;       // K byte sub-offset: 0 or 16
  const int ra = m0 + lm;
  f32x16 acc[4];
  #pragma unroll
  for (int t = 0; t < 4; ++t)
    #pragma unroll
    for (int q = 0; q < 16; ++q) acc[t][q] = 0.f;

  for (int kc = 0; kc < 128; kc += 64) {
    #pragma unroll
    for (int u = 0; u < 4; ++u) {     // stage A chunk: 128 rows x 64 K, f32->bf16
      const int i = tid + 256 * u;
      const int r = i >> 3, k8 = (i & 7) << 3;
      uint4 o = make_uint4(0u, 0u, 0u, 0u);
      if (r < rows) {
        const float* ap = A + (size_t)(n0 + r) * 128 + kc + k8;
        const float4 a = *(const float4*)(ap);
        const float4 b = *(const float4*)(ap + 4);
        o.x = bfpack(a.x, a.y); o.y = bfpack(a.z, a.w);
        o.z = bfpack(b.x, b.y); o.w = bfpack(b.z, b.w);
      }
      *(uint4*)(hsb + ((r * 128 + k8 * 2) ^ ((r & 7) << 4))) = o;
    }
    #pragma unroll
    for (int u = 0; u < 4; ++u) {     // stage WT chunk: 128 n x 64 K (bf16)
      const int i = tid + 256 * u;
      const int nn = i >> 3, k8 = (i & 7) << 3;
      const uint4 v = *(const uint4*)(WT + nn * 128 + kc + k8);
      *(uint4*)(wsb + ((nn * 128 + k8 * 2) ^ ((nn & 7) << 4))) = v;
    }
    __syncthreads();
    #pragma unroll
    for (int ks = 0; ks < 4; ++ks) {
      const int kb = ks * 32 + lkb;
      const bf16x8 af = *(const bf16x8*)(hsb + ((ra * 128 + kb) ^ ((ra & 7) << 4)));
      #pragma unroll
      for (int t = 0; t < 4; ++t) {
        const int rb = t * 32 + lm;
        const bf16x8 bfr = *(const bf16x8*)(wsb + ((rb * 128 + kb) ^ ((rb & 7) << 4)));
        acc[t] = __builtin_amdgcn_mfma_f32_32x32x16_bf16(af, bfr, acc[t], 0, 0, 0);
      }
    }
    __syncthreads();
  }

  #pragma unroll
  for (int t = 0; t < 4; ++t) {
    #pragma unroll
    for (int q = 0; q < 16; ++q) {
      const int m = m0 + (q & 3) + ((q >> 2) << 3) + ((l >> 5) << 2);
      if (m < rows) hw[(size_t)(n0 + m) * 128 + t * 32 + lm] = f2bf(acc[t][q]);
    }
  }
}

// ---- mega0: [gemm1 MFMA (blocks first) | deg count, XCD-partitioned] ------
__global__ __launch_bounds__(256, 2) void k_mega0(
    const float* __restrict__ x, const unsigned short* __restrict__ WT1,
    unsigned short* __restrict__ hw, int N, int gb,
    const int* __restrict__ coli, int E, int* __restrict__ degi) {
  __shared__ __align__(16) unsigned short hs[128 * 64];   // 16KB
  __shared__ __align__(16) unsigned short wsm[128 * 64];  // 16KB
  if ((int)blockIdx.x < gb) {
    gemm_mfma_f32in_body(x, WT1, hw, N, blockIdx.x * 128, (char*)hs, (char*)wsm);
  } else {
    const int bb = (int)blockIdx.x - gb;
    const int xcd = (int)blockIdx.x & 7;   // presumed XCD (round-robin)
    const int chunk = bb >> 3;
    const int nsz = (N + 7) >> 3;
    const int clo = xcd * nsz;
    const int chi = min(clo + nsz, N);
    const int ebase = chunk * 8192;
    #pragma unroll
    for (int it = 0; it < 8; ++it) {
      const int e = ebase + it * 1024 + (int)threadIdx.x * 4;
      if (e + 3 < E) {
        const int4 c4 = *(const int4*)(coli + e);
        if (c4.x >= clo && c4.x < chi) atomicAdd(&degi[c4.x], 1);
        if (c4.y >= clo && c4.y < chi) atomicAdd(&degi[c4.y], 1);
        if (c4.z >= clo && c4.z < chi) atomicAdd(&degi[c4.z], 1);
        if (c4.w >= clo && c4.w < chi) atomicAdd(&degi[c4.w], 1);
      } else {
        for (int ee = e; ee < E; ++ee) {
          const int c = coli[ee];
          if (c >= clo && c < chi) atomicAdd(&degi[c], 1);
        }
      }
    }
  }
}

// ---- scan1: dense deg -> dinv + block-local offs + bsums ------------------
__global__ __launch_bounds__(256) void k_scan1(
    const int* __restrict__ degi, int N, int* __restrict__ offs,
    int* __restrict__ bsums, float* __restrict__ dinv) {
  __shared__ int sm[256];
  const int b = blockIdx.x, t = threadIdx.x;
  const int base = b * 1024 + t * 4;
  int v[4];
  #pragma unroll
  for (int i = 0; i < 4; ++i) v[i] = (base + i < N) ? degi[base + i] : 0;
  #pragma unroll
  for (int i = 0; i < 4; ++i)
    if (base + i < N) dinv[base + i] = rsqrtf(1.0f + (float)v[i]);
  const int s = v[0] + v[1] + v[2] + v[3];
  sm[t] = s;
  __syncthreads();
  for (int ofs = 1; ofs < 256; ofs <<= 1) {
    const int add = (t >= ofs) ? sm[t - ofs] : 0;
    __syncthreads();
    sm[t] += add;
    __syncthreads();
  }
  if (t == 255) bsums[b] = sm[255];
  int run = sm[t] - s;
  #pragma unroll
  for (int i = 0; i < 4; ++i) {
    if (base + i < N) offs[base + i] = run;
    run += v[i];
  }
}

// ---- scan3f (fused scan2+3): global offsets + cursor init -----------------
__global__ __launch_bounds__(256) void k_scan3f(
    int* __restrict__ offs, const int* __restrict__ bsums,
    int* __restrict__ cursor, int nb, int N) {
  __shared__ int sm[128];
  const int t = threadIdx.x;
  if (t < 128) sm[t] = (t < nb) ? bsums[t] : 0;
  __syncthreads();
  for (int ofs = 1; ofs < 128; ofs <<= 1) {
    int add = 0;
    if (t < 128 && t >= ofs) add = sm[t - ofs];
    __syncthreads();
    if (t < 128) sm[t] += add;
    __syncthreads();
  }
  const int add = (blockIdx.x == 0) ? 0 : sm[blockIdx.x - 1];
  const int base = blockIdx.x * 1024 + t * 4;
  #pragma unroll
  for (int i = 0; i < 4; ++i) {
    const int idx = base + i;
    if (idx < N) {
      const int o = offs[idx] + add;
      offs[idx] = o;
      cursor[idx] = o;
    }
  }
}

// ---- fill: XCD-partitioned scatter (plain stores -> L2 write-combining) ---
__global__ __launch_bounds__(256) void k_fill(
    const int* __restrict__ rowi, const int* __restrict__ coli,
    int* __restrict__ cursor, int* __restrict__ sorted_row, int E, int N) {
  const int xcd = (int)blockIdx.x & 7;   // presumed XCD (round-robin)
  const int chunk = (int)blockIdx.x >> 3;
  const int nsz = (N + 7) >> 3;
  const int clo = xcd * nsz;
  const int chi = min(clo + nsz, N);
  const int ebase = chunk * 8192;
  #pragma unroll
  for (int it = 0; it < 8; ++it) {
    const int e = ebase + it * 1024 + (int)threadIdx.x * 4;
    if (e + 3 < E) {
      const int4 c4 = *(const int4*)(coli + e);
      const int4 r4 = *(const int4*)(rowi + e);
      int p;
      if (c4.x >= clo && c4.x < chi) { p = atomicAdd(&cursor[c4.x], 1); sorted_row[p] = r4.x; }
      if (c4.y >= clo && c4.y < chi) { p = atomicAdd(&cursor[c4.y], 1); sorted_row[p] = r4.y; }
      if (c4.z >= clo && c4.z < chi) { p = atomicAdd(&cursor[c4.z], 1); sorted_row[p] = r4.z; }
      if (c4.w >= clo && c4.w < chi) { p = atomicAdd(&cursor[c4.w], 1); sorted_row[p] = r4.w; }
    } else {
      for (int ee = e; ee < E; ++ee) {
        const int c = coli[ee];
        if (c >= clo && c < chi) {
          const int p = atomicAdd(&cursor[c], 1);
          sorted_row[p] = rowi[ee];
        }
      }
    }
  }
}

// ---- MFMA GEMM (layers 2,3): full-K 64KB LDS (proven r13) -----------------
__global__ __launch_bounds__(256, 2) void k_gemm_mfma(
    const unsigned short* __restrict__ A, long long lda,
    const unsigned short* __restrict__ WT, unsigned short* __restrict__ hw,
    int N) {
  __shared__ __align__(16) unsigned short hs[128 * 128];
  __shared__ __align__(16) unsigned short WsT[128 * 128];
  const int tid = threadIdx.x;
  const int n0 = blockIdx.x * 128;
  const int rows = min(128, N - n0);
  char* hsb = (char*)hs;
  char* wsb = (char*)WsT;

  #pragma unroll
  for (int u = 0; u < 8; ++u) {
    const int i = tid + 256 * u;
    const int r = i >> 4, k8 = (i & 15) << 3;
    uint4 v = make_uint4(0u, 0u, 0u, 0u);
    if (r < rows) v = *(const uint4*)(A + (size_t)(n0 + r) * lda + k8);
    *(uint4*)(hsb + ((r * 256 + k8 * 2) ^ ((r & 7) << 4))) = v;
  }
  #pragma unroll
  for (int u = 0; u < 8; ++u) {
    const int i = tid + 256 * u;
    const int nn = i >> 4, k8 = (i & 15) << 3;
    const uint4 v = *(const uint4*)(WT + nn * 128 + k8);
    *(uint4*)(wsb + ((nn * 256 + k8 * 2) ^ ((nn & 7) << 4))) = v;
  }
  __syncthreads();

  const int l = tid & 63;
  const int m0 = (tid >> 6) << 5;
  const int lm = l & 31;
  const int lk = (l >> 5) << 3;
  const int ra = m0 + lm;
  f32x16 acc[4];
  #pragma unroll
  for (int t = 0; t < 4; ++t)
    #pragma unroll
    for (int q = 0; q < 16; ++q) acc[t][q] = 0.f;

  #pragma unroll
  for (int ks = 0; ks < 8; ++ks) {
    const int kb = (ks * 16 + lk) * 2;
    const bf16x8 af = *(const bf16x8*)(hsb + ((ra * 256 + kb) ^ ((ra & 7) << 4)));
    #pragma unroll
    for (int t = 0; t < 4; ++t) {
      const int rb = t * 32 + lm;
      const bf16x8 bfr = *(const bf16x8*)(wsb + ((rb * 256 + kb) ^ ((rb & 7) << 4)));
      acc[t] = __builtin_amdgcn_mfma_f32_32x32x16_bf16(af, bfr, acc[t], 0, 0, 0);
    }
  }

  #pragma unroll
  for (int t = 0; t < 4; ++t) {
    #pragma unroll
    for (int q = 0; q < 16; ++q) {
      const int m = m0 + (q & 3) + ((q >> 2) << 3) + ((l >> 5) << 2);
      if (m < rows) hw[(size_t)(n0 + m) * 128 + t * 32 + lm] = f2bf(acc[t][q]);
    }
  }
}

// ---- MFMA final: out = hcat(bf16) @ Wlin + blin, 3 K-chunks of 128 --------
__global__ __launch_bounds__(256, 2) void k_final_mfma(
    const unsigned short* __restrict__ hcat, const unsigned short* __restrict__ WTL,
    const float* __restrict__ blin, float* __restrict__ out, int N) {
  __shared__ __align__(16) unsigned short hs[128 * 128];
  __shared__ __align__(16) unsigned short WsT[64 * 128];
  const int tid = threadIdx.x;
  const int n0 = blockIdx.x * 128;
  const int rows = min(128, N - n0);
  char* hsb = (char*)hs;
  char* wsb = (char*)WsT;

  const int l = tid & 63;
  const int m0 = (tid >> 6) << 5;
  const int lm = l & 31;
  const int lk = (l >> 5) << 3;
  const int ra = m0 + lm;
  f32x16 acc[2];
  #pragma unroll
  for (int t = 0; t < 2; ++t)
    #pragma unroll
    for (int q = 0; q < 16; ++q) acc[t][q] = 0.f;

  for (int kc = 0; kc < 384; kc += 128) {
    #pragma unroll
    for (int u = 0; u < 8; ++u) {
      const int i = tid + 256 * u;
      const int r = i >> 4, k8 = (i & 15) << 3;
      uint4 v = make_uint4(0u, 0u, 0u, 0u);
      if (r < rows) v = *(const uint4*)(hcat + (size_t)(n0 + r) * 384 + kc + k8);
      *(uint4*)(hsb + ((r * 256 + k8 * 2) ^ ((r & 7) << 4))) = v;
    }
    #pragma unroll
    for (int u = 0; u < 4; ++u) {
      const int i = tid + 256 * u;
      const int nn = i >> 4, k8 = (i & 15) << 3;
      const uint4 v = *(const uint4*)(WTL + nn * 384 + kc + k8);
      *(uint4*)(wsb + ((nn * 256 + k8 * 2) ^ ((nn & 7) << 4))) = v;
    }
    __syncthreads();

    #pragma unroll
    for (int ks = 0; ks < 8; ++ks) {
      const int kb = (ks * 16 + lk) * 2;
      const bf16x8 af = *(const bf16x8*)(hsb + ((ra * 256 + kb) ^ ((ra & 7) << 4)));
      #pragma unroll
      for (int t = 0; t < 2; ++t) {
        const int rb = t * 32 + lm;
        const bf16x8 bfr = *(const bf16x8*)(wsb + ((rb * 256 + kb) ^ ((rb & 7) << 4)));
        acc[t] = __builtin_amdgcn_mfma_f32_32x32x16_bf16(af, bfr, acc[t], 0, 0, 0);
      }
    }
    __syncthreads();
  }

  #pragma unroll
  for (int t = 0; t < 2; ++t) {
    const float bb = blin[t * 32 + lm];
    #pragma unroll
    for (int q = 0; q < 16; ++q) {
      const int m = m0 + (q & 3) + ((q >> 2) << 3) + ((l >> 5) << 2);
      if (m < rows) out[(size_t)(n0 + m) * 64 + t * 32 + lm] = acc[t][q] + bb;
    }
  }
}

// ---- segment aggregate (32 lanes/node, ushort4/lane, 8-deep gather) -------
__global__ __launch_bounds__(256) void k_agg(
    const int* __restrict__ offs, const int* __restrict__ degi,
    const int* __restrict__ sorted_row, const float* __restrict__ dinv,
    const unsigned short* __restrict__ hw, const float* __restrict__ bias,
    unsigned short* __restrict__ hcat, int koff, int N) {
  const int g = (int)((blockIdx.x * 256 + threadIdx.x) >> 5);
  if (g >= N) return;
  const int j = (threadIdx.x & 31) << 2;
  const float dc = dinv[g];
  float acc[4];
  {
    const uint2 sv = *(const uint2*)(hw + (size_t)g * 128 + j);
    float f[4];
    bf4_unpack(sv, f);
    #pragma unroll
    for (int q = 0; q < 4; ++q) acc[q] = dc * f[q];
  }

  const int off = offs[g];
  const int end = off + degi[g];
  int e = off;
  for (; e + 7 < end; e += 8) {
    int r[8];
    #pragma unroll
    for (int t = 0; t < 8; ++t) r[t] = sorted_row[e + t];
    float dr[8];
    uint2 v[8];
    #pragma unroll
    for (int t = 0; t < 8; ++t) {
      dr[t] = dinv[r[t]];
      v[t] = *(const uint2*)(hw + (size_t)r[t] * 128 + j);
    }
    #pragma unroll
    for (int t = 0; t < 8; ++t) {
      float f[4];
      bf4_unpack(v[t], f);
      #pragma unroll
      for (int q = 0; q < 4; ++q) acc[q] = fmaf(dr[t], f[q], acc[q]);
    }
  }
  for (; e + 3 < end; e += 4) {
    int r[4];
    #pragma unroll
    for (int t = 0; t < 4; ++t) r[t] = sorted_row[e + t];
    float dr[4];
    uint2 v[4];
    #pragma unroll
    for (int t = 0; t < 4; ++t) {
      dr[t] = dinv[r[t]];
      v[t] = *(const uint2*)(hw + (size_t)r[t] * 128 + j);
    }
    #pragma unroll
    for (int t = 0; t < 4; ++t) {
      float f[4];
      bf4_unpack(v[t], f);
      #pragma unroll
      for (int q = 0; q < 4; ++q) acc[q] = fmaf(dr[t], f[q], acc[q]);
    }
  }
  for (; e < end; ++e) {
    const int r0 = sorted_row[e];
    const float d0 = dinv[r0];
    const uint2 v0 = *(const uint2*)(hw + (size_t)r0 * 128 + j);
    float f[4];
    bf4_unpack(v0, f);
    #pragma unroll
    for (int q = 0; q < 4; ++q) acc[q] = fmaf(d0, f[q], acc[q]);
  }

  const float4 bb = *(const float4*)(bias + j);
  const float o0 = fmaxf(fmaf(dc, acc[0], bb.x), 0.f);
  const float o1 = fmaxf(fmaf(dc, acc[1], bb.y), 0.f);
  const float o2 = fmaxf(fmaf(dc, acc[2], bb.z), 0.f);
  const float o3 = fmaxf(fmaf(dc, acc[3], bb.w), 0.f);
  uint2 st;
  st.x = bfpack(o0, o1);
  st.y = bfpack(o2, o3);
  *(uint2*)(hcat + (size_t)g * 384 + koff + j) = st;
}

extern "C" void kernel_launch(void* const* d_in, const int* in_sizes, int n_in,
                              void* d_out, int out_size, void* d_ws, size_t ws_size,
                              hipStream_t stream) {
  const float* x    = (const float*)d_in[0];
  const int*   ei   = (const int*)d_in[1];
  const float* W1   = (const float*)d_in[2];
  const float* b1   = (const float*)d_in[3];
  const float* W2   = (const float*)d_in[4];
  const float* b2   = (const float*)d_in[5];
  const float* W3   = (const float*)d_in[6];
  const float* b3   = (const float*)d_in[7];
  const float* Wlin = (const float*)d_in[8];
  const float* blin = (const float*)d_in[9];

  const int N = in_sizes[0] / 128;
  const int E = in_sizes[1] / 2;
  const int* rowi = ei;
  const int* coli = ei + E;

  // ws: degi | cursor | dinv | offs | bsums | sorted_row | WT* | hw | hcat
  char* ws = (char*)d_ws;
  const size_t nb4 = (((size_t)N * 4) + 255) & ~(size_t)255;
  int*   degi       = (int*)ws;                 ws += nb4;
  int*   cursor     = (int*)ws;                 ws += nb4;
  float* dinv       = (float*)ws;               ws += nb4;
  int*   offs       = (int*)ws;                 ws += nb4;
  int*   bsums      = (int*)ws;                 ws += 1024;
  int*   sorted_row = (int*)ws;                 ws += (((size_t)E * 4) + 255) & ~(size_t)255;
  unsigned short* WT1  = (unsigned short*)ws;   ws += 128 * 128 * 2;
  unsigned short* WT2  = (unsigned short*)ws;   ws += 128 * 128 * 2;
  unsigned short* WT3  = (unsigned short*)ws;   ws += 128 * 128 * 2;
  unsigned short* WTL  = (unsigned short*)ws;   ws += 64 * 384 * 2;
  unsigned short* hw   = (unsigned short*)ws;   ws += (size_t)N * 128 * 2;
  unsigned short* hcat = (unsigned short*)ws;

  const int nblk = (N + 1023) / 1024;  // <= 128
  const int gemmBlocks = (N + 127) / 128;
  const int nCh = (E + 8191) / 8192;   // edge chunks of 8192
  const int partBlocks = nCh * 8;      // x8 XCD ranges
  const int aggBlocks  = (N + 7) / 8;

  k_wt<<<(49152 + 24576 + 255) / 256, 256, 0, stream>>>(W1, W2, W3, Wlin,
                                                        WT1, WT2, WT3, WTL);
  hipMemsetAsync(degi, 0, (size_t)N * 4, stream);
  k_mega0<<<gemmBlocks + partBlocks, 256, 0, stream>>>(x, WT1, hw, N, gemmBlocks,
                                                       coli, E, degi);
  k_scan1<<<nblk, 256, 0, stream>>>(degi, N, offs, bsums, dinv);
  k_scan3f<<<nblk, 256, 0, stream>>>(offs, bsums, cursor, nblk, N);
  k_fill<<<partBlocks, 256, 0, stream>>>(rowi, coli, cursor, sorted_row, E, N);

  k_agg<<<aggBlocks, 256, 0, stream>>>(offs, degi, sorted_row, dinv, hw,
                                       b1, hcat, 0, N);
  k_gemm_mfma<<<gemmBlocks, 256, 0, stream>>>(hcat, 384, WT2, hw, N);
  k_agg<<<aggBlocks, 256, 0, stream>>>(offs, degi, sorted_row, dinv, hw,
                                       b2, hcat, 128, N);
  k_gemm_mfma<<<gemmBlocks, 256, 0, stream>>>(hcat + 128, 384, WT3, hw, N);
  k_agg<<<aggBlocks, 256, 0, stream>>>(offs, degi, sorted_row, dinv, hw,
                                       b3, hcat, 256, N);
  k_final_mfma<<<gemmBlocks, 256, 0, stream>>>(hcat, WTL, blin, (float*)d_out, N);
}

// Round 20
// 381.691 us; speedup vs baseline: 1.1833x; 1.0986x over previous
//
#include <hip/hip_runtime.h>
#include <hip/hip_bf16.h>

// ---------------------------------------------------------------------------
// GCN via device-built CSR, all tensors bf16, all GEMMs MFMA.
// r20: CSR build via partial-histogram counting sort -- ZERO global atomics
// (r17-r19 showed deg/fill pinned at L2 atomic-unit floor ~78us each):
//   32 edge-chunks x 8 XCD-aligned col-ranges = 256 blocks.
//   mega0 = [gemm1 MFMA | hist: LDS histogram -> private partial slice]
//   scan1: deg[c] = sum_ch partial + dinv + offs ; scan3f: global offs
//   cpre:  partial[ch][c] <- offs[c] + prefix_ch (in-place span starts)
//   fill2: LDS cursors from partial row; LDS atomicAdd -> plain stores
//   3x [ agg -> hcat bf16 ; gemm_{k+1} MFMA ] ; final MFMA
// MFMA: mfma_f32_32x32x16_bf16, LDS XOR swizzle byte^=(row&7)<<4,
// C/D map col=lane&31, row=(q&3)+8*(q>>2)+4*(lane>>5) [verified r13/r14].
// MAXNSZ=12544 supports N <= 100352 (harness N=100000).
// ---------------------------------------------------------------------------

#define MAXNSZ 12544

typedef __attribute__((ext_vector_type(8))) short bf16x8;
typedef __attribute__((ext_vector_type(16))) float f32x16;

__device__ __forceinline__ unsigned short f2bf(float f) {  // RNE f32->bf16
  unsigned int u = __float_as_uint(f);
  u += 0x7FFFu + ((u >> 16) & 1u);
  return (unsigned short)(u >> 16);
}
__device__ __forceinline__ unsigned int bfpack(float a, float b) {
  return ((unsigned int)f2bf(a)) | ((unsigned int)f2bf(b) << 16);
}
__device__ __forceinline__ void bf4_unpack(uint2 v, float* f) {
  f[0] = __uint_as_float(v.x << 16); f[1] = __uint_as_float(v.x & 0xFFFF0000u);
  f[2] = __uint_as_float(v.y << 16); f[3] = __uint_as_float(v.y & 0xFFFF0000u);
}

// ---- weight transposes: W1..W3 -> WT[128][128]; Wlin -> WTL[64][384] ------
__global__ __launch_bounds__(256) void k_wt(
    const float* __restrict__ W1, const float* __restrict__ W2,
    const float* __restrict__ W3, const float* __restrict__ Wlin,
    unsigned short* __restrict__ WT1, unsigned short* __restrict__ WT2,
    unsigned short* __restrict__ WT3, unsigned short* __restrict__ WTL) {
  const int idx = blockIdx.x * 256 + threadIdx.x;  // 49152 + 24576
  if (idx < 49152) {
    const int w = idx >> 14;
    const int rem = idx & 16383;
    const int n = rem >> 7, k = rem & 127;
    const float* W = (w == 0) ? W1 : (w == 1) ? W2 : W3;
    unsigned short* WT = (w == 0) ? WT1 : (w == 1) ? WT2 : WT3;
    WT[n * 128 + k] = f2bf(W[k * 128 + n]);
  } else if (idx < 49152 + 24576) {
    const int rem = idx - 49152;
    const int n = rem / 384, k = rem - n * 384;
    WTL[n * 384 + k] = f2bf(Wlin[k * 64 + n]);
  }
}

// ---- MFMA GEMM body, f32 A input (convert in staging), BK=64 --------------
__device__ __forceinline__ void gemm_mfma_f32in_body(
    const float* __restrict__ A, const unsigned short* __restrict__ WT,
    unsigned short* __restrict__ hw, int N, int n0, char* hsb, char* wsb) {
  const int tid = threadIdx.x;
  const int rows = min(128, N - n0);
  const int l = tid & 63;
  const int m0 = (tid >> 6) << 5;
  const int lm = l & 31;
  const int lkb = (l >> 5) << 4;       // K byte sub-offset: 0 or 16
  const int ra = m0 + lm;
  f32x16 acc[4];
  #pragma unroll
  for (int t = 0; t < 4; ++t)
    #pragma unroll
    for (int q = 0; q < 16; ++q) acc[t][q] = 0.f;

  for (int kc = 0; kc < 128; kc += 64) {
    #pragma unroll
    for (int u = 0; u < 4; ++u) {     // stage A chunk: 128 rows x 64 K, f32->bf16
      const int i = tid + 256 * u;
      const int r = i >> 3, k8 = (i & 7) << 3;
      uint4 o = make_uint4(0u, 0u, 0u, 0u);
      if (r < rows) {
        const float* ap = A + (size_t)(n0 + r) * 128 + kc + k8;
        const float4 a = *(const float4*)(ap);
        const float4 b = *(const float4*)(ap + 4);
        o.x = bfpack(a.x, a.y); o.y = bfpack(a.z, a.w);
        o.z = bfpack(b.x, b.y); o.w = bfpack(b.z, b.w);
      }
      *(uint4*)(hsb + ((r * 128 + k8 * 2) ^ ((r & 7) << 4))) = o;
    }
    #pragma unroll
    for (int u = 0; u < 4; ++u) {     // stage WT chunk: 128 n x 64 K (bf16)
      const int i = tid + 256 * u;
      const int nn = i >> 3, k8 = (i & 7) << 3;
      const uint4 v = *(const uint4*)(WT + nn * 128 + kc + k8);
      *(uint4*)(wsb + ((nn * 128 + k8 * 2) ^ ((nn & 7) << 4))) = v;
    }
    __syncthreads();
    #pragma unroll
    for (int ks = 0; ks < 4; ++ks) {
      const int kb = ks * 32 + lkb;
      const bf16x8 af = *(const bf16x8*)(hsb + ((ra * 128 + kb) ^ ((ra & 7) << 4)));
      #pragma unroll
      for (int t = 0; t < 4; ++t) {
        const int rb = t * 32 + lm;
        const bf16x8 bfr = *(const bf16x8*)(wsb + ((rb * 128 + kb) ^ ((rb & 7) << 4)));
        acc[t] = __builtin_amdgcn_mfma_f32_32x32x16_bf16(af, bfr, acc[t], 0, 0, 0);
      }
    }
    __syncthreads();
  }

  #pragma unroll
  for (int t = 0; t < 4; ++t) {
    #pragma unroll
    for (int q = 0; q < 16; ++q) {
      const int m = m0 + (q & 3) + ((q >> 2) << 3) + ((l >> 5) << 2);
      if (m < rows) hw[(size_t)(n0 + m) * 128 + t * 32 + lm] = f2bf(acc[t][q]);
    }
  }
}

// ---- mega0: [gemm1 MFMA (blocks first) | LDS histogram -> partial] --------
// Shared 50KB buffer: gemm uses first 32KB (hs 16K + ws 16K); hist uses all.
__global__ __launch_bounds__(256, 2) void k_mega0(
    const float* __restrict__ x, const unsigned short* __restrict__ WT1,
    unsigned short* __restrict__ hw, int N, int gb,
    const int* __restrict__ coli, int E, int CH,
    int* __restrict__ partial, int nsz) {
  __shared__ __align__(16) char buf[MAXNSZ * 4];
  if ((int)blockIdx.x < gb) {
    gemm_mfma_f32in_body(x, WT1, hw, N, blockIdx.x * 128,
                         buf, buf + 16384);
  } else {
    int* lh = (int*)buf;
    const int bb = (int)blockIdx.x - gb;      // bb = chunk*8 + range
    const int rg = bb & 7, chunk = bb >> 3;
    const int clo = rg * nsz;
    const int chi = min(clo + nsz, N);
    for (int i = threadIdx.x; i < nsz; i += 256) lh[i] = 0;
    __syncthreads();
    const int e0 = chunk * CH;
    const int e1 = min(e0 + CH, E);
    for (int e = e0 + (int)threadIdx.x * 4; e < e1; e += 1024) {
      if (e + 3 < e1) {
        const int4 c4 = *(const int4*)(coli + e);
        if (c4.x >= clo && c4.x < chi) atomicAdd(&lh[c4.x - clo], 1);
        if (c4.y >= clo && c4.y < chi) atomicAdd(&lh[c4.y - clo], 1);
        if (c4.z >= clo && c4.z < chi) atomicAdd(&lh[c4.z - clo], 1);
        if (c4.w >= clo && c4.w < chi) atomicAdd(&lh[c4.w - clo], 1);
      } else {
        for (int ee = e; ee < e1; ++ee) {
          const int c = coli[ee];
          if (c >= clo && c < chi) atomicAdd(&lh[c - clo], 1);
        }
      }
    }
    __syncthreads();
    int* pp = partial + (size_t)bb * nsz;
    for (int i = threadIdx.x; i < nsz; i += 256) pp[i] = lh[i];
  }
}

// ---- scan1: deg = sum of 32 partials -> degc,dinv + local offs + bsums ----
__global__ __launch_bounds__(256) void k_scan1(
    const int* __restrict__ partial, int nsz, int N, int* __restrict__ degc,
    int* __restrict__ offs, int* __restrict__ bsums, float* __restrict__ dinv) {
  __shared__ int sm[256];
  const int b = blockIdx.x, t = threadIdx.x;
  const int base = b * 1024 + t * 4;
  int v[4];
  #pragma unroll
  for (int i = 0; i < 4; ++i) {
    const int c = base + i;
    int s = 0;
    if (c < N) {
      const int rg = c / nsz, lc = c - rg * nsz;
      const int* p = partial + (size_t)rg * nsz + lc;
      #pragma unroll
      for (int ch = 0; ch < 32; ++ch) s += p[(size_t)ch * 8 * nsz];
      degc[c] = s;
      dinv[c] = rsqrtf(1.0f + (float)s);
    }
    v[i] = (c < N) ? s : 0;
  }
  const int s = v[0] + v[1] + v[2] + v[3];
  sm[t] = s;
  __syncthreads();
  for (int ofs = 1; ofs < 256; ofs <<= 1) {
    const int add = (t >= ofs) ? sm[t - ofs] : 0;
    __syncthreads();
    sm[t] += add;
    __syncthreads();
  }
  if (t == 255) bsums[b] = sm[255];
  int run = sm[t] - s;
  #pragma unroll
  for (int i = 0; i < 4; ++i) {
    if (base + i < N) offs[base + i] = run;
    run += v[i];
  }
}

// ---- scan3f (fused scan2+3): global offsets -------------------------------
__global__ __launch_bounds__(256) void k_scan3f(
    int* __restrict__ offs, const int* __restrict__ bsums, int nb, int N) {
  __shared__ int sm[128];
  const int t = threadIdx.x;
  if (t < 128) sm[t] = (t < nb) ? bsums[t] : 0;
  __syncthreads();
  for (int ofs = 1; ofs < 128; ofs <<= 1) {
    int add = 0;
    if (t < 128 && t >= ofs) add = sm[t - ofs];
    __syncthreads();
    if (t < 128) sm[t] += add;
    __syncthreads();
  }
  const int add = (blockIdx.x == 0) ? 0 : sm[blockIdx.x - 1];
  const int base = blockIdx.x * 1024 + t * 4;
  #pragma unroll
  for (int i = 0; i < 4; ++i) {
    const int idx = base + i;
    if (idx < N) offs[idx] += add;
  }
}

// ---- cpre: in-place convert partial counts -> per-chunk span starts -------
__global__ __launch_bounds__(256) void k_cpre(
    int* __restrict__ partial, const int* __restrict__ offs, int nsz, int N) {
  const int c = blockIdx.x * 256 + threadIdx.x;
  if (c >= N) return;
  const int rg = c / nsz, lc = c - rg * nsz;
  int* p = partial + (size_t)rg * nsz + lc;
  int running = offs[c];
  #pragma unroll
  for (int ch = 0; ch < 32; ++ch) {
    int* q = p + (size_t)ch * 8 * nsz;
    const int tmp = *q;
    *q = running;
    running += tmp;
  }
}

// ---- fill2: LDS cursors (no global atomics), XCD-local stores -------------
__global__ __launch_bounds__(256) void k_fill2(
    const int* __restrict__ rowi, const int* __restrict__ coli,
    const int* __restrict__ partial, int* __restrict__ sorted_row,
    int E, int CH, int N, int nsz) {
  __shared__ int cur[MAXNSZ];
  const int bb = (int)blockIdx.x;            // bb = chunk*8 + range
  const int rg = bb & 7, chunk = bb >> 3;
  const int clo = rg * nsz;
  const int chi = min(clo + nsz, N);
  const int* pp = partial + (size_t)bb * nsz;
  for (int i = threadIdx.x; i < nsz; i += 256) cur[i] = pp[i];
  __syncthreads();
  const int e0 = chunk * CH;
  const int e1 = min(e0 + CH, E);
  for (int e = e0 + (int)threadIdx.x * 4; e < e1; e += 1024) {
    if (e + 3 < e1) {
      const int4 c4 = *(const int4*)(coli + e);
      const int4 r4 = *(const int4*)(rowi + e);
      int p;
      if (c4.x >= clo && c4.x < chi) { p = atomicAdd(&cur[c4.x - clo], 1); sorted_row[p] = r4.x; }
      if (c4.y >= clo && c4.y < chi) { p = atomicAdd(&cur[c4.y - clo], 1); sorted_row[p] = r4.y; }
      if (c4.z >= clo && c4.z < chi) { p = atomicAdd(&cur[c4.z - clo], 1); sorted_row[p] = r4.z; }
      if (c4.w >= clo && c4.w < chi) { p = atomicAdd(&cur[c4.w - clo], 1); sorted_row[p] = r4.w; }
    } else {
      for (int ee = e; ee < e1; ++ee) {
        const int c = coli[ee];
        if (c >= clo && c < chi) {
          const int p = atomicAdd(&cur[c - clo], 1);
          sorted_row[p] = rowi[ee];
        }
      }
    }
  }
}

// ---- MFMA GEMM (layers 2,3): full-K 64KB LDS (proven r13) -----------------
__global__ __launch_bounds__(256, 2) void k_gemm_mfma(
    const unsigned short* __restrict__ A, long long lda,
    const unsigned short* __restrict__ WT, unsigned short* __restrict__ hw,
    int N) {
  __shared__ __align__(16) unsigned short hs[128 * 128];
  __shared__ __align__(16) unsigned short WsT[128 * 128];
  const int tid = threadIdx.x;
  const int n0 = blockIdx.x * 128;
  const int rows = min(128, N - n0);
  char* hsb = (char*)hs;
  char* wsb = (char*)WsT;

  #pragma unroll
  for (int u = 0; u < 8; ++u) {
    const int i = tid + 256 * u;
    const int r = i >> 4, k8 = (i & 15) << 3;
    uint4 v = make_uint4(0u, 0u, 0u, 0u);
    if (r < rows) v = *(const uint4*)(A + (size_t)(n0 + r) * lda + k8);
    *(uint4*)(hsb + ((r * 256 + k8 * 2) ^ ((r & 7) << 4))) = v;
  }
  #pragma unroll
  for (int u = 0; u < 8; ++u) {
    const int i = tid + 256 * u;
    const int nn = i >> 4, k8 = (i & 15) << 3;
    const uint4 v = *(const uint4*)(WT + nn * 128 + k8);
    *(uint4*)(wsb + ((nn * 256 + k8 * 2) ^ ((nn & 7) << 4))) = v;
  }
  __syncthreads();

  const int l = tid & 63;
  const int m0 = (tid >> 6) << 5;
  const int lm = l & 31;
  const int lk = (l >> 5) << 3;
  const int ra = m0 + lm;
  f32x16 acc[4];
  #pragma unroll
  for (int t = 0; t < 4; ++t)
    #pragma unroll
    for (int q = 0; q < 16; ++q) acc[t][q] = 0.f;

  #pragma unroll
  for (int ks = 0; ks < 8; ++ks) {
    const int kb = (ks * 16 + lk) * 2;
    const bf16x8 af = *(const bf16x8*)(hsb + ((ra * 256 + kb) ^ ((ra & 7) << 4)));
    #pragma unroll
    for (int t = 0; t < 4; ++t) {
      const int rb = t * 32 + lm;
      const bf16x8 bfr = *(const bf16x8*)(wsb + ((rb * 256 + kb) ^ ((rb & 7) << 4)));
      acc[t] = __builtin_amdgcn_mfma_f32_32x32x16_bf16(af, bfr, acc[t], 0, 0, 0);
    }
  }

  #pragma unroll
  for (int t = 0; t < 4; ++t) {
    #pragma unroll
    for (int q = 0; q < 16; ++q) {
      const int m = m0 + (q & 3) + ((q >> 2) << 3) + ((l >> 5) << 2);
      if (m < rows) hw[(size_t)(n0 + m) * 128 + t * 32 + lm] = f2bf(acc[t][q]);
    }
  }
}

// ---- MFMA final: out = hcat(bf16) @ Wlin + blin, 3 K-chunks of 128 --------
__global__ __launch_bounds__(256, 2) void k_final_mfma(
    const unsigned short* __restrict__ hcat, const unsigned short* __restrict__ WTL,
    const float* __restrict__ blin, float* __restrict__ out, int N) {
  __shared__ __align__(16) unsigned short hs[128 * 128];
  __shared__ __align__(16) unsigned short WsT[64 * 128];
  const int tid = threadIdx.x;
  const int n0 = blockIdx.x * 128;
  const int rows = min(128, N - n0);
  char* hsb = (char*)hs;
  char* wsb = (char*)WsT;

  const int l = tid & 63;
  const int m0 = (tid >> 6) << 5;
  const int lm = l & 31;
  const int lk = (l >> 5) << 3;
  const int ra = m0 + lm;
  f32x16 acc[2];
  #pragma unroll
  for (int t = 0; t < 2; ++t)
    #pragma unroll
    for (int q = 0; q < 16; ++q) acc[t][q] = 0.f;

  for (int kc = 0; kc < 384; kc += 128) {
    #pragma unroll
    for (int u = 0; u < 8; ++u) {
      const int i = tid + 256 * u;
      const int r = i >> 4, k8 = (i & 15) << 3;
      uint4 v = make_uint4(0u, 0u, 0u, 0u);
      if (r < rows) v = *(const uint4*)(hcat + (size_t)(n0 + r) * 384 + kc + k8);
      *(uint4*)(hsb + ((r * 256 + k8 * 2) ^ ((r & 7) << 4))) = v;
    }
    #pragma unroll
    for (int u = 0; u < 4; ++u) {
      const int i = tid + 256 * u;
      const int nn = i >> 4, k8 = (i & 15) << 3;
      const uint4 v = *(const uint4*)(WTL + nn * 384 + kc + k8);
      *(uint4*)(wsb + ((nn * 256 + k8 * 2) ^ ((nn & 7) << 4))) = v;
    }
    __syncthreads();

    #pragma unroll
    for (int ks = 0; ks < 8; ++ks) {
      const int kb = (ks * 16 + lk) * 2;
      const bf16x8 af = *(const bf16x8*)(hsb + ((ra * 256 + kb) ^ ((ra & 7) << 4)));
      #pragma unroll
      for (int t = 0; t < 2; ++t) {
        const int rb = t * 32 + lm;
        const bf16x8 bfr = *(const bf16x8*)(wsb + ((rb * 256 + kb) ^ ((rb & 7) << 4)));
        acc[t] = __builtin_amdgcn_mfma_f32_32x32x16_bf16(af, bfr, acc[t], 0, 0, 0);
      }
    }
    __syncthreads();
  }

  #pragma unroll
  for (int t = 0; t < 2; ++t) {
    const float bb = blin[t * 32 + lm];
    #pragma unroll
    for (int q = 0; q < 16; ++q) {
      const int m = m0 + (q & 3) + ((q >> 2) << 3) + ((l >> 5) << 2);
      if (m < rows) out[(size_t)(n0 + m) * 64 + t * 32 + lm] = acc[t][q] + bb;
    }
  }
}

// ---- segment aggregate (32 lanes/node, ushort4/lane, 8-deep gather) -------
__global__ __launch_bounds__(256) void k_agg(
    const int* __restrict__ offs, const int* __restrict__ degi,
    const int* __restrict__ sorted_row, const float* __restrict__ dinv,
    const unsigned short* __restrict__ hw, const float* __restrict__ bias,
    unsigned short* __restrict__ hcat, int koff, int N) {
  const int g = (int)((blockIdx.x * 256 + threadIdx.x) >> 5);
  if (g >= N) return;
  const int j = (threadIdx.x & 31) << 2;
  const float dc = dinv[g];
  float acc[4];
  {
    const uint2 sv = *(const uint2*)(hw + (size_t)g * 128 + j);
    float f[4];
    bf4_unpack(sv, f);
    #pragma unroll
    for (int q = 0; q < 4; ++q) acc[q] = dc * f[q];
  }

  const int off = offs[g];
  const int end = off + degi[g];
  int e = off;
  for (; e + 7 < end; e += 8) {
    int r[8];
    #pragma unroll
    for (int t = 0; t < 8; ++t) r[t] = sorted_row[e + t];
    float dr[8];
    uint2 v[8];
    #pragma unroll
    for (int t = 0; t < 8; ++t) {
      dr[t] = dinv[r[t]];
      v[t] = *(const uint2*)(hw + (size_t)r[t] * 128 + j);
    }
    #pragma unroll
    for (int t = 0; t < 8; ++t) {
      float f[4];
      bf4_unpack(v[t], f);
      #pragma unroll
      for (int q = 0; q < 4; ++q) acc[q] = fmaf(dr[t], f[q], acc[q]);
    }
  }
  for (; e + 3 < end; e += 4) {
    int r[4];
    #pragma unroll
    for (int t = 0; t < 4; ++t) r[t] = sorted_row[e + t];
    float dr[4];
    uint2 v[4];
    #pragma unroll
    for (int t = 0; t < 4; ++t) {
      dr[t] = dinv[r[t]];
      v[t] = *(const uint2*)(hw + (size_t)r[t] * 128 + j);
    }
    #pragma unroll
    for (int t = 0; t < 4; ++t) {
      float f[4];
      bf4_unpack(v[t], f);
      #pragma unroll
      for (int q = 0; q < 4; ++q) acc[q] = fmaf(dr[t], f[q], acc[q]);
    }
  }
  for (; e < end; ++e) {
    const int r0 = sorted_row[e];
    const float d0 = dinv[r0];
    const uint2 v0 = *(const uint2*)(hw + (size_t)r0 * 128 + j);
    float f[4];
    bf4_unpack(v0, f);
    #pragma unroll
    for (int q = 0; q < 4; ++q) acc[q] = fmaf(d0, f[q], acc[q]);
  }

  const float4 bb = *(const float4*)(bias + j);
  const float o0 = fmaxf(fmaf(dc, acc[0], bb.x), 0.f);
  const float o1 = fmaxf(fmaf(dc, acc[1], bb.y), 0.f);
  const float o2 = fmaxf(fmaf(dc, acc[2], bb.z), 0.f);
  const float o3 = fmaxf(fmaf(dc, acc[3], bb.w), 0.f);
  uint2 st;
  st.x = bfpack(o0, o1);
  st.y = bfpack(o2, o3);
  *(uint2*)(hcat + (size_t)g * 384 + koff + j) = st;
}

extern "C" void kernel_launch(void* const* d_in, const int* in_sizes, int n_in,
                              void* d_out, int out_size, void* d_ws, size_t ws_size,
                              hipStream_t stream) {
  const float* x    = (const float*)d_in[0];
  const int*   ei   = (const int*)d_in[1];
  const float* W1   = (const float*)d_in[2];
  const float* b1   = (const float*)d_in[3];
  const float* W2   = (const float*)d_in[4];
  const float* b2   = (const float*)d_in[5];
  const float* W3   = (const float*)d_in[6];
  const float* b3   = (const float*)d_in[7];
  const float* Wlin = (const float*)d_in[8];
  const float* blin = (const float*)d_in[9];

  const int N = in_sizes[0] / 128;
  const int E = in_sizes[1] / 2;
  const int* rowi = ei;
  const int* coli = ei + E;

  const int nsz = (N + 7) / 8;                     // per-range counters (<= MAXNSZ)
  const int CH  = (((E + 31) / 32) + 3) & ~3;      // edges per chunk, mult of 4

  // ws: degc | dinv | offs | bsums | partial(256*nsz) | sorted_row | WT* | hw | hcat
  char* ws = (char*)d_ws;
  const size_t nb4 = (((size_t)N * 4) + 255) & ~(size_t)255;
  int*   degc       = (int*)ws;                 ws += nb4;
  float* dinv       = (float*)ws;               ws += nb4;
  int*   offs       = (int*)ws;                 ws += nb4;
  int*   bsums      = (int*)ws;                 ws += 1024;
  int*   partial    = (int*)ws;                 ws += (((size_t)256 * nsz * 4) + 255) & ~(size_t)255;
  int*   sorted_row = (int*)ws;                 ws += (((size_t)E * 4) + 255) & ~(size_t)255;
  unsigned short* WT1  = (unsigned short*)ws;   ws += 128 * 128 * 2;
  unsigned short* WT2  = (unsigned short*)ws;   ws += 128 * 128 * 2;
  unsigned short* WT3  = (unsigned short*)ws;   ws += 128 * 128 * 2;
  unsigned short* WTL  = (unsigned short*)ws;   ws += 64 * 384 * 2;
  unsigned short* hw   = (unsigned short*)ws;   ws += (size_t)N * 128 * 2;
  unsigned short* hcat = (unsigned short*)ws;

  const int nblk = (N + 1023) / 1024;  // <= 128
  const int gemmBlocks = (N + 127) / 128;
  const int aggBlocks  = (N + 7) / 8;

  k_wt<<<(49152 + 24576 + 255) / 256, 256, 0, stream>>>(W1, W2, W3, Wlin,
                                                        WT1, WT2, WT3, WTL);
  k_mega0<<<gemmBlocks + 256, 256, 0, stream>>>(x, WT1, hw, N, gemmBlocks,
                                                coli, E, CH, partial, nsz);
  k_scan1<<<nblk, 256, 0, stream>>>(partial, nsz, N, degc, offs, bsums, dinv);
  k_scan3f<<<nblk, 256, 0, stream>>>(offs, bsums, nblk, N);
  k_cpre<<<(N + 255) / 256, 256, 0, stream>>>(partial, offs, nsz, N);
  k_fill2<<<256, 256, 0, stream>>>(rowi, coli, partial, sorted_row, E, CH, N, nsz);

  k_agg<<<aggBlocks, 256, 0, stream>>>(offs, degc, sorted_row, dinv, hw,
                                       b1, hcat, 0, N);
  k_gemm_mfma<<<gemmBlocks, 256, 0, stream>>>(hcat, 384, WT2, hw, N);
  k_agg<<<aggBlocks, 256, 0, stream>>>(offs, degc, sorted_row, dinv, hw,
                                       b2, hcat, 128, N);
  k_gemm_mfma<<<gemmBlocks, 256, 0, stream>>>(hcat + 128, 384, WT3, hw, N);
  k_agg<<<aggBlocks, 256, 0, stream>>>(offs, degc, sorted_row, dinv, hw,
                                       b3, hcat, 256, N);
  k_final_mfma<<<gemmBlocks, 256, 0, stream>>>(hcat, WTL, blin, (float*)d_out, N);
}

// Round 21
// 365.409 us; speedup vs baseline: 1.2360x; 1.0446x over previous
//
#include <hip/hip_runtime.h>
#include <hip/hip_bf16.h>

// ---------------------------------------------------------------------------
// GCN via device-built CSR, all tensors bf16, all GEMMs MFMA.
// CSR build: partial-histogram counting sort, ZERO global atomics (r20).
// r21 re-tile for occupancy (r20: mega0 Occ 20% @50KB LDS; fill2 1 block/CU):
//   64 edge-chunks x 16 col-ranges = 1024 blocks (XCD-consistent: bb%8=rg%8).
//   nsz ~= N/16 -> 25KB LDS cursors/hist; mega0 buf 32KB + bounds(256,3).
//   mega0 = [gemm1 MFMA | hist: LDS histogram -> private partial slice]
//   scan1 (sum 64 partials) ; scan3f ; cpre ; fill2 (LDS cursors)
//   3x [ agg -> hcat bf16 ; gemm_{k+1} MFMA ] ; final MFMA
// MFMA: mfma_f32_32x32x16_bf16, LDS XOR swizzle byte^=(row&7)<<4,
// C/D map col=lane&31, row=(q&3)+8*(q>>2)+4*(lane>>5) [verified r13/r14].
// MAXNSZ=6400 supports N <= 102400 (harness N=100000).
// ---------------------------------------------------------------------------

#define MAXNSZ 6400
#define NCHUNK 64
#define NRANGE 16

typedef __attribute__((ext_vector_type(8))) short bf16x8;
typedef __attribute__((ext_vector_type(16))) float f32x16;

__device__ __forceinline__ unsigned short f2bf(float f) {  // RNE f32->bf16
  unsigned int u = __float_as_uint(f);
  u += 0x7FFFu + ((u >> 16) & 1u);
  return (unsigned short)(u >> 16);
}
__device__ __forceinline__ unsigned int bfpack(float a, float b) {
  return ((unsigned int)f2bf(a)) | ((unsigned int)f2bf(b) << 16);
}
__device__ __forceinline__ void bf4_unpack(uint2 v, float* f) {
  f[0] = __uint_as_float(v.x << 16); f[1] = __uint_as_float(v.x & 0xFFFF0000u);
  f[2] = __uint_as_float(v.y << 16); f[3] = __uint_as_float(v.y & 0xFFFF0000u);
}

// ---- weight transposes: W1..W3 -> WT[128][128]; Wlin -> WTL[64][384] ------
__global__ __launch_bounds__(256) void k_wt(
    const float* __restrict__ W1, const float* __restrict__ W2,
    const float* __restrict__ W3, const float* __restrict__ Wlin,
    unsigned short* __restrict__ WT1, unsigned short* __restrict__ WT2,
    unsigned short* __restrict__ WT3, unsigned short* __restrict__ WTL) {
  const int idx = blockIdx.x * 256 + threadIdx.x;  // 49152 + 24576
  if (idx < 49152) {
    const int w = idx >> 14;
    const int rem = idx & 16383;
    const int n = rem >> 7, k = rem & 127;
    const float* W = (w == 0) ? W1 : (w == 1) ? W2 : W3;
    unsigned short* WT = (w == 0) ? WT1 : (w == 1) ? WT2 : WT3;
    WT[n * 128 + k] = f2bf(W[k * 128 + n]);
  } else if (idx < 49152 + 24576) {
    const int rem = idx - 49152;
    const int n = rem / 384, k = rem - n * 384;
    WTL[n * 384 + k] = f2bf(Wlin[k * 64 + n]);
  }
}

// ---- MFMA GEMM body, f32 A input (convert in staging), BK=64 --------------
__device__ __forceinline__ void gemm_mfma_f32in_body(
    const float* __restrict__ A, const unsigned short* __restrict__ WT,
    unsigned short* __restrict__ hw, int N, int n0, char* hsb, char* wsb) {
  const int tid = threadIdx.x;
  const int rows = min(128, N - n0);
  const int l = tid & 63;
  const int m0 = (tid >> 6) << 5;
  const int lm = l & 31;
  const int lkb = (l >> 5) << 4;       // K byte sub-offset: 0 or 16
  const int ra = m0 + lm;
  f32x16 acc[4];
  #pragma unroll
  for (int t = 0; t < 4; ++t)
    #pragma unroll
    for (int q = 0; q < 16; ++q) acc[t][q] = 0.f;

  for (int kc = 0; kc < 128; kc += 64) {
    #pragma unroll
    for (int u = 0; u < 4; ++u) {     // stage A chunk: 128 rows x 64 K, f32->bf16
      const int i = tid + 256 * u;
      const int r = i >> 3, k8 = (i & 7) << 3;
      uint4 o = make_uint4(0u, 0u, 0u, 0u);
      if (r < rows) {
        const float* ap = A + (size_t)(n0 + r) * 128 + kc + k8;
        const float4 a = *(const float4*)(ap);
        const float4 b = *(const float4*)(ap + 4);
        o.x = bfpack(a.x, a.y); o.y = bfpack(a.z, a.w);
        o.z = bfpack(b.x, b.y); o.w = bfpack(b.z, b.w);
      }
      *(uint4*)(hsb + ((r * 128 + k8 * 2) ^ ((r & 7) << 4))) = o;
    }
    #pragma unroll
    for (int u = 0; u < 4; ++u) {     // stage WT chunk: 128 n x 64 K (bf16)
      const int i = tid + 256 * u;
      const int nn = i >> 3, k8 = (i & 7) << 3;
      const uint4 v = *(const uint4*)(WT + nn * 128 + kc + k8);
      *(uint4*)(wsb + ((nn * 128 + k8 * 2) ^ ((nn & 7) << 4))) = v;
    }
    __syncthreads();
    #pragma unroll
    for (int ks = 0; ks < 4; ++ks) {
      const int kb = ks * 32 + lkb;
      const bf16x8 af = *(const bf16x8*)(hsb + ((ra * 128 + kb) ^ ((ra & 7) << 4)));
      #pragma unroll
      for (int t = 0; t < 4; ++t) {
        const int rb = t * 32 + lm;
        const bf16x8 bfr = *(const bf16x8*)(wsb + ((rb * 128 + kb) ^ ((rb & 7) << 4)));
        acc[t] = __builtin_amdgcn_mfma_f32_32x32x16_bf16(af, bfr, acc[t], 0, 0, 0);
      }
    }
    __syncthreads();
  }

  #pragma unroll
  for (int t = 0; t < 4; ++t) {
    #pragma unroll
    for (int q = 0; q < 16; ++q) {
      const int m = m0 + (q & 3) + ((q >> 2) << 3) + ((l >> 5) << 2);
      if (m < rows) hw[(size_t)(n0 + m) * 128 + t * 32 + lm] = f2bf(acc[t][q]);
    }
  }
}

// ---- mega0: [gemm1 MFMA (blocks first) | LDS histogram -> partial] --------
// 32KB buffer: gemm uses 16K+16K; hist uses nsz*4 <= 25.6KB of it.
__global__ __launch_bounds__(256, 3) void k_mega0(
    const float* __restrict__ x, const unsigned short* __restrict__ WT1,
    unsigned short* __restrict__ hw, int N, int gb,
    const int* __restrict__ coli, int E, int CH,
    int* __restrict__ partial, int nsz) {
  __shared__ __align__(16) char buf[32768];
  if ((int)blockIdx.x < gb) {
    gemm_mfma_f32in_body(x, WT1, hw, N, blockIdx.x * 128, buf, buf + 16384);
  } else {
    int* lh = (int*)buf;
    const int bb = (int)blockIdx.x - gb;      // bb = chunk*16 + range
    const int rg = bb & (NRANGE - 1), chunk = bb >> 4;
    const int clo = rg * nsz;
    const int chi = min(clo + nsz, N);
    for (int i = threadIdx.x; i < nsz; i += 256) lh[i] = 0;
    __syncthreads();
    const int e0 = chunk * CH;
    const int e1 = min(e0 + CH, E);
    for (int e = e0 + (int)threadIdx.x * 4; e < e1; e += 1024) {
      if (e + 3 < e1) {
        const int4 c4 = *(const int4*)(coli + e);
        if (c4.x >= clo && c4.x < chi) atomicAdd(&lh[c4.x - clo], 1);
        if (c4.y >= clo && c4.y < chi) atomicAdd(&lh[c4.y - clo], 1);
        if (c4.z >= clo && c4.z < chi) atomicAdd(&lh[c4.z - clo], 1);
        if (c4.w >= clo && c4.w < chi) atomicAdd(&lh[c4.w - clo], 1);
      } else {
        for (int ee = e; ee < e1; ++ee) {
          const int c = coli[ee];
          if (c >= clo && c < chi) atomicAdd(&lh[c - clo], 1);
        }
      }
    }
    __syncthreads();
    int* pp = partial + (size_t)bb * nsz;
    for (int i = threadIdx.x; i < nsz; i += 256) pp[i] = lh[i];
  }
}

// ---- scan1: deg = sum of NCHUNK partials -> degc,dinv + local offs + bsums -
__global__ __launch_bounds__(256) void k_scan1(
    const int* __restrict__ partial, int nsz, int N, int* __restrict__ degc,
    int* __restrict__ offs, int* __restrict__ bsums, float* __restrict__ dinv) {
  __shared__ int sm[256];
  const int b = blockIdx.x, t = threadIdx.x;
  const int base = b * 1024 + t * 4;
  int v[4];
  #pragma unroll
  for (int i = 0; i < 4; ++i) {
    const int c = base + i;
    int s = 0;
    if (c < N) {
      const int rg = c / nsz, lc = c - rg * nsz;
      const int* p = partial + (size_t)rg * nsz + lc;
      #pragma unroll 8
      for (int ch = 0; ch < NCHUNK; ++ch) s += p[(size_t)ch * NRANGE * nsz];
      degc[c] = s;
      dinv[c] = rsqrtf(1.0f + (float)s);
    }
    v[i] = (c < N) ? s : 0;
  }
  const int s = v[0] + v[1] + v[2] + v[3];
  sm[t] = s;
  __syncthreads();
  for (int ofs = 1; ofs < 256; ofs <<= 1) {
    const int add = (t >= ofs) ? sm[t - ofs] : 0;
    __syncthreads();
    sm[t] += add;
    __syncthreads();
  }
  if (t == 255) bsums[b] = sm[255];
  int run = sm[t] - s;
  #pragma unroll
  for (int i = 0; i < 4; ++i) {
    if (base + i < N) offs[base + i] = run;
    run += v[i];
  }
}

// ---- scan3f (fused scan2+3): global offsets -------------------------------
__global__ __launch_bounds__(256) void k_scan3f(
    int* __restrict__ offs, const int* __restrict__ bsums, int nb, int N) {
  __shared__ int sm[128];
  const int t = threadIdx.x;
  if (t < 128) sm[t] = (t < nb) ? bsums[t] : 0;
  __syncthreads();
  for (int ofs = 1; ofs < 128; ofs <<= 1) {
    int add = 0;
    if (t < 128 && t >= ofs) add = sm[t - ofs];
    __syncthreads();
    if (t < 128) sm[t] += add;
    __syncthreads();
  }
  const int add = (blockIdx.x == 0) ? 0 : sm[blockIdx.x - 1];
  const int base = blockIdx.x * 1024 + t * 4;
  #pragma unroll
  for (int i = 0; i < 4; ++i) {
    const int idx = base + i;
    if (idx < N) offs[idx] += add;
  }
}

// ---- cpre: in-place convert partial counts -> per-chunk span starts -------
__global__ __launch_bounds__(256) void k_cpre(
    int* __restrict__ partial, const int* __restrict__ offs, int nsz, int N) {
  const int c = blockIdx.x * 256 + threadIdx.x;
  if (c >= N) return;
  const int rg = c / nsz, lc = c - rg * nsz;
  int* p = partial + (size_t)rg * nsz + lc;
  int running = offs[c];
  #pragma unroll 8
  for (int ch = 0; ch < NCHUNK; ++ch) {
    int* q = p + (size_t)ch * NRANGE * nsz;
    const int tmp = *q;
    *q = running;
    running += tmp;
  }
}

// ---- fill2: LDS cursors (no global atomics), XCD-consistent stores --------
__global__ __launch_bounds__(256) void k_fill2(
    const int* __restrict__ rowi, const int* __restrict__ coli,
    const int* __restrict__ partial, int* __restrict__ sorted_row,
    int E, int CH, int N, int nsz) {
  __shared__ int cur[MAXNSZ];
  const int bb = (int)blockIdx.x;            // bb = chunk*16 + range
  const int rg = bb & (NRANGE - 1), chunk = bb >> 4;
  const int clo = rg * nsz;
  const int chi = min(clo + nsz, N);
  const int* pp = partial + (size_t)bb * nsz;
  for (int i = threadIdx.x; i < nsz; i += 256) cur[i] = pp[i];
  __syncthreads();
  const int e0 = chunk * CH;
  const int e1 = min(e0 + CH, E);
  for (int e = e0 + (int)threadIdx.x * 4; e < e1; e += 1024) {
    if (e + 3 < e1) {
      const int4 c4 = *(const int4*)(coli + e);
      const int4 r4 = *(const int4*)(rowi + e);
      int p;
      if (c4.x >= clo && c4.x < chi) { p = atomicAdd(&cur[c4.x - clo], 1); sorted_row[p] = r4.x; }
      if (c4.y >= clo && c4.y < chi) { p = atomicAdd(&cur[c4.y - clo], 1); sorted_row[p] = r4.y; }
      if (c4.z >= clo && c4.z < chi) { p = atomicAdd(&cur[c4.z - clo], 1); sorted_row[p] = r4.z; }
      if (c4.w >= clo && c4.w < chi) { p = atomicAdd(&cur[c4.w - clo], 1); sorted_row[p] = r4.w; }
    } else {
      for (int ee = e; ee < e1; ++ee) {
        const int c = coli[ee];
        if (c >= clo && c < chi) {
          const int p = atomicAdd(&cur[c - clo], 1);
          sorted_row[p] = rowi[ee];
        }
      }
    }
  }
}

// ---- MFMA GEMM (layers 2,3): full-K 64KB LDS (proven r13) -----------------
__global__ __launch_bounds__(256, 2) void k_gemm_mfma(
    const unsigned short* __restrict__ A, long long lda,
    const unsigned short* __restrict__ WT, unsigned short* __restrict__ hw,
    int N) {
  __shared__ __align__(16) unsigned short hs[128 * 128];
  __shared__ __align__(16) unsigned short WsT[128 * 128];
  const int tid = threadIdx.x;
  const int n0 = blockIdx.x * 128;
  const int rows = min(128, N - n0);
  char* hsb = (char*)hs;
  char* wsb = (char*)WsT;

  #pragma unroll
  for (int u = 0; u < 8; ++u) {
    const int i = tid + 256 * u;
    const int r = i >> 4, k8 = (i & 15) << 3;
    uint4 v = make_uint4(0u, 0u, 0u, 0u);
    if (r < rows) v = *(const uint4*)(A + (size_t)(n0 + r) * lda + k8);
    *(uint4*)(hsb + ((r * 256 + k8 * 2) ^ ((r & 7) << 4))) = v;
  }
  #pragma unroll
  for (int u = 0; u < 8; ++u) {
    const int i = tid + 256 * u;
    const int nn = i >> 4, k8 = (i & 15) << 3;
    const uint4 v = *(const uint4*)(WT + nn * 128 + k8);
    *(uint4*)(wsb + ((nn * 256 + k8 * 2) ^ ((nn & 7) << 4))) = v;
  }
  __syncthreads();

  const int l = tid & 63;
  const int m0 = (tid >> 6) << 5;
  const int lm = l & 31;
  const int lk = (l >> 5) << 3;
  const int ra = m0 + lm;
  f32x16 acc[4];
  #pragma unroll
  for (int t = 0; t < 4; ++t)
    #pragma unroll
    for (int q = 0; q < 16; ++q) acc[t][q] = 0.f;

  #pragma unroll
  for (int ks = 0; ks < 8; ++ks) {
    const int kb = (ks * 16 + lk) * 2;
    const bf16x8 af = *(const bf16x8*)(hsb + ((ra * 256 + kb) ^ ((ra & 7) << 4)));
    #pragma unroll
    for (int t = 0; t < 4; ++t) {
      const int rb = t * 32 + lm;
      const bf16x8 bfr = *(const bf16x8*)(wsb + ((rb * 256 + kb) ^ ((rb & 7) << 4)));
      acc[t] = __builtin_amdgcn_mfma_f32_32x32x16_bf16(af, bfr, acc[t], 0, 0, 0);
    }
  }

  #pragma unroll
  for (int t = 0; t < 4; ++t) {
    #pragma unroll
    for (int q = 0; q < 16; ++q) {
      const int m = m0 + (q & 3) + ((q >> 2) << 3) + ((l >> 5) << 2);
      if (m < rows) hw[(size_t)(n0 + m) * 128 + t * 32 + lm] = f2bf(acc[t][q]);
    }
  }
}

// ---- MFMA final: out = hcat(bf16) @ Wlin + blin, 3 K-chunks of 128 --------
__global__ __launch_bounds__(256, 2) void k_final_mfma(
    const unsigned short* __restrict__ hcat, const unsigned short* __restrict__ WTL,
    const float* __restrict__ blin, float* __restrict__ out, int N) {
  __shared__ __align__(16) unsigned short hs[128 * 128];
  __shared__ __align__(16) unsigned short WsT[64 * 128];
  const int tid = threadIdx.x;
  const int n0 = blockIdx.x * 128;
  const int rows = min(128, N - n0);
  char* hsb = (char*)hs;
  char* wsb = (char*)WsT;

  const int l = tid & 63;
  const int m0 = (tid >> 6) << 5;
  const int lm = l & 31;
  const int lk = (l >> 5) << 3;
  const int ra = m0 + lm;
  f32x16 acc[2];
  #pragma unroll
  for (int t = 0; t < 2; ++t)
    #pragma unroll
    for (int q = 0; q < 16; ++q) acc[t][q] = 0.f;

  for (int kc = 0; kc < 384; kc += 128) {
    #pragma unroll
    for (int u = 0; u < 8; ++u) {
      const int i = tid + 256 * u;
      const int r = i >> 4, k8 = (i & 15) << 3;
      uint4 v = make_uint4(0u, 0u, 0u, 0u);
      if (r < rows) v = *(const uint4*)(hcat + (size_t)(n0 + r) * 384 + kc + k8);
      *(uint4*)(hsb + ((r * 256 + k8 * 2) ^ ((r & 7) << 4))) = v;
    }
    #pragma unroll
    for (int u = 0; u < 4; ++u) {
      const int i = tid + 256 * u;
      const int nn = i >> 4, k8 = (i & 15) << 3;
      const uint4 v = *(const uint4*)(WTL + nn * 384 + kc + k8);
      *(uint4*)(wsb + ((nn * 256 + k8 * 2) ^ ((nn & 7) << 4))) = v;
    }
    __syncthreads();

    #pragma unroll
    for (int ks = 0; ks < 8; ++ks) {
      const int kb = (ks * 16 + lk) * 2;
      const bf16x8 af = *(const bf16x8*)(hsb + ((ra * 256 + kb) ^ ((ra & 7) << 4)));
      #pragma unroll
      for (int t = 0; t < 2; ++t) {
        const int rb = t * 32 + lm;
        const bf16x8 bfr = *(const bf16x8*)(wsb + ((rb * 256 + kb) ^ ((rb & 7) << 4)));
        acc[t] = __builtin_amdgcn_mfma_f32_32x32x16_bf16(af, bfr, acc[t], 0, 0, 0);
      }
    }
    __syncthreads();
  }

  #pragma unroll
  for (int t = 0; t < 2; ++t) {
    const float bb = blin[t * 32 + lm];
    #pragma unroll
    for (int q = 0; q < 16; ++q) {
      const int m = m0 + (q & 3) + ((q >> 2) << 3) + ((l >> 5) << 2);
      if (m < rows) out[(size_t)(n0 + m) * 64 + t * 32 + lm] = acc[t][q] + bb;
    }
  }
}

// ---- segment aggregate (32 lanes/node, ushort4/lane, 8-deep gather) -------
__global__ __launch_bounds__(256) void k_agg(
    const int* __restrict__ offs, const int* __restrict__ degi,
    const int* __restrict__ sorted_row, const float* __restrict__ dinv,
    const unsigned short* __restrict__ hw, const float* __restrict__ bias,
    unsigned short* __restrict__ hcat, int koff, int N) {
  const int g = (int)((blockIdx.x * 256 + threadIdx.x) >> 5);
  if (g >= N) return;
  const int j = (threadIdx.x & 31) << 2;
  const float dc = dinv[g];
  float acc[4];
  {
    const uint2 sv = *(const uint2*)(hw + (size_t)g * 128 + j);
    float f[4];
    bf4_unpack(sv, f);
    #pragma unroll
    for (int q = 0; q < 4; ++q) acc[q] = dc * f[q];
  }

  const int off = offs[g];
  const int end = off + degi[g];
  int e = off;
  for (; e + 7 < end; e += 8) {
    int r[8];
    #pragma unroll
    for (int t = 0; t < 8; ++t) r[t] = sorted_row[e + t];
    float dr[8];
    uint2 v[8];
    #pragma unroll
    for (int t = 0; t < 8; ++t) {
      dr[t] = dinv[r[t]];
      v[t] = *(const uint2*)(hw + (size_t)r[t] * 128 + j);
    }
    #pragma unroll
    for (int t = 0; t < 8; ++t) {
      float f[4];
      bf4_unpack(v[t], f);
      #pragma unroll
      for (int q = 0; q < 4; ++q) acc[q] = fmaf(dr[t], f[q], acc[q]);
    }
  }
  for (; e + 3 < end; e += 4) {
    int r[4];
    #pragma unroll
    for (int t = 0; t < 4; ++t) r[t] = sorted_row[e + t];
    float dr[4];
    uint2 v[4];
    #pragma unroll
    for (int t = 0; t < 4; ++t) {
      dr[t] = dinv[r[t]];
      v[t] = *(const uint2*)(hw + (size_t)r[t] * 128 + j);
    }
    #pragma unroll
    for (int t = 0; t < 4; ++t) {
      float f[4];
      bf4_unpack(v[t], f);
      #pragma unroll
      for (int q = 0; q < 4; ++q) acc[q] = fmaf(dr[t], f[q], acc[q]);
    }
  }
  for (; e < end; ++e) {
    const int r0 = sorted_row[e];
    const float d0 = dinv[r0];
    const uint2 v0 = *(const uint2*)(hw + (size_t)r0 * 128 + j);
    float f[4];
    bf4_unpack(v0, f);
    #pragma unroll
    for (int q = 0; q < 4; ++q) acc[q] = fmaf(d0, f[q], acc[q]);
  }

  const float4 bb = *(const float4*)(bias + j);
  const float o0 = fmaxf(fmaf(dc, acc[0], bb.x), 0.f);
  const float o1 = fmaxf(fmaf(dc, acc[1], bb.y), 0.f);
  const float o2 = fmaxf(fmaf(dc, acc[2], bb.z), 0.f);
  const float o3 = fmaxf(fmaf(dc, acc[3], bb.w), 0.f);
  uint2 st;
  st.x = bfpack(o0, o1);
  st.y = bfpack(o2, o3);
  *(uint2*)(hcat + (size_t)g * 384 + koff + j) = st;
}

extern "C" void kernel_launch(void* const* d_in, const int* in_sizes, int n_in,
                              void* d_out, int out_size, void* d_ws, size_t ws_size,
                              hipStream_t stream) {
  const float* x    = (const float*)d_in[0];
  const int*   ei   = (const int*)d_in[1];
  const float* W1   = (const float*)d_in[2];
  const float* b1   = (const float*)d_in[3];
  const float* W2   = (const float*)d_in[4];
  const float* b2   = (const float*)d_in[5];
  const float* W3   = (const float*)d_in[6];
  const float* b3   = (const float*)d_in[7];
  const float* Wlin = (const float*)d_in[8];
  const float* blin = (const float*)d_in[9];

  const int N = in_sizes[0] / 128;
  const int E = in_sizes[1] / 2;
  const int* rowi = ei;
  const int* coli = ei + E;

  const int nsz = (N + NRANGE - 1) / NRANGE;            // <= MAXNSZ
  const int CH  = (((E + NCHUNK - 1) / NCHUNK) + 3) & ~3;
  const int nPart = NCHUNK * NRANGE;                    // 1024 blocks

  // ws: degc | dinv | offs | bsums | partial | sorted_row | WT* | hw | hcat
  char* ws = (char*)d_ws;
  const size_t nb4 = (((size_t)N * 4) + 255) & ~(size_t)255;
  int*   degc       = (int*)ws;                 ws += nb4;
  float* dinv       = (float*)ws;               ws += nb4;
  int*   offs       = (int*)ws;                 ws += nb4;
  int*   bsums      = (int*)ws;                 ws += 1024;
  int*   partial    = (int*)ws;                 ws += (((size_t)nPart * nsz * 4) + 255) & ~(size_t)255;
  int*   sorted_row = (int*)ws;                 ws += (((size_t)E * 4) + 255) & ~(size_t)255;
  unsigned short* WT1  = (unsigned short*)ws;   ws += 128 * 128 * 2;
  unsigned short* WT2  = (unsigned short*)ws;   ws += 128 * 128 * 2;
  unsigned short* WT3  = (unsigned short*)ws;   ws += 128 * 128 * 2;
  unsigned short* WTL  = (unsigned short*)ws;   ws += 64 * 384 * 2;
  unsigned short* hw   = (unsigned short*)ws;   ws += (size_t)N * 128 * 2;
  unsigned short* hcat = (unsigned short*)ws;

  const int nblk = (N + 1023) / 1024;  // <= 128
  const int gemmBlocks = (N + 127) / 128;
  const int aggBlocks  = (N + 7) / 8;

  k_wt<<<(49152 + 24576 + 255) / 256, 256, 0, stream>>>(W1, W2, W3, Wlin,
                                                        WT1, WT2, WT3, WTL);
  k_mega0<<<gemmBlocks + nPart, 256, 0, stream>>>(x, WT1, hw, N, gemmBlocks,
                                                  coli, E, CH, partial, nsz);
  k_scan1<<<nblk, 256, 0, stream>>>(partial, nsz, N, degc, offs, bsums, dinv);
  k_scan3f<<<nblk, 256, 0, stream>>>(offs, bsums, nblk, N);
  k_cpre<<<(N + 255) / 256, 256, 0, stream>>>(partial, offs, nsz, N);
  k_fill2<<<nPart, 256, 0, stream>>>(rowi, coli, partial, sorted_row, E, CH, N, nsz);

  k_agg<<<aggBlocks, 256, 0, stream>>>(offs, degc, sorted_row, dinv, hw,
                                       b1, hcat, 0, N);
  k_gemm_mfma<<<gemmBlocks, 256, 0, stream>>>(hcat, 384, WT2, hw, N);
  k_agg<<<aggBlocks, 256, 0, stream>>>(offs, degc, sorted_row, dinv, hw,
                                       b2, hcat, 128, N);
  k_gemm_mfma<<<gemmBlocks, 256, 0, stream>>>(hcat + 128, 384, WT3, hw, N);
  k_agg<<<aggBlocks, 256, 0, stream>>>(offs, degc, sorted_row, dinv, hw,
                                       b3, hcat, 256, N);
  k_final_mfma<<<gemmBlocks, 256, 0, stream>>>(hcat, WTL, blin, (float*)d_out, N);
}